// Round 11
// baseline (150.075 us; speedup 1.0000x reference)
//
#include <hip/hip_runtime.h>
#include <cstddef>
#include <cstdint>

// ReBased linear attention, round 11.
// r10 post-mortem: attn is LDS-pipe-bound (16 waves x ~14 ds_read_b128/step
// ~= 2700cyc/step on the single LDS pipe -- matches measured 2775). Rebuild
// attention on mfma_f32_32x32x16_bf16 (2x FLOP/read), P kept in registers via
// cvt-pack + v_permlane32_swap_b32 (VALU, no LDS), wave owns 64 q-rows (frag
// reads amortized over 2 q-subtiles). 4-wave quad blocks, grid (32 bh, 8).
// GEMMs / casts / LN unchanged from r10.

typedef __attribute__((ext_vector_type(8)))  __bf16 bf16x8;
typedef __attribute__((ext_vector_type(2)))  __bf16 bf16x2;
typedef __attribute__((ext_vector_type(4)))  float  f32x4;
typedef __attribute__((ext_vector_type(16))) float  f32x16;
typedef __attribute__((ext_vector_type(8)))  unsigned short ushort8;
typedef __attribute__((ext_vector_type(4)))  unsigned short ushort4v;
typedef __attribute__((ext_vector_type(4)))  unsigned int   uint4v;

__device__ __forceinline__ unsigned short f2b(float f) {
    union { float f; unsigned u; } v; v.f = f;
    unsigned r = v.u + 0x7FFFu + ((v.u >> 16) & 1u);   // RNE
    return (unsigned short)(r >> 16);
}
__device__ __forceinline__ float b2f(unsigned short b) {
    union { unsigned u; float f; } v; v.u = ((unsigned)b) << 16;
    return v.f;
}
__device__ __forceinline__ unsigned pk2(float a, float b) {
    bf16x2 p; p[0] = (__bf16)a; p[1] = (__bf16)b;
    return __builtin_bit_cast(unsigned, p);
}

typedef const __attribute__((address_space(1))) void* gas_ptr;
typedef __attribute__((address_space(3))) void* las_ptr;

__device__ __forceinline__ void gload_lds16(const unsigned short* g, unsigned short* l) {
    // 16B/lane; LDS dest = wave-uniform base + lane*16
    __builtin_amdgcn_global_load_lds((gas_ptr)g, (las_ptr)l, 16, 0, 0);
}

// ---------------- bf16 MFMA GEMM, 2-phase dbuf: C = A @ W^T ----------------
template <int BM, int BN, int OUTMODE>
__global__ __launch_bounds__(256) void gemm_mfma(const unsigned short* __restrict__ A,
                                                 const unsigned short* __restrict__ W,
                                                 void* __restrict__ Cout,
                                                 int M, int N, int K) {
    constexpr int BK = 64;
    constexpr int MF = BM / 32;
    constexpr int NF = BN / 32;
    __shared__ __align__(16) unsigned short As[2][BM * BK];
    __shared__ __align__(16) unsigned short Bs[2][BN * BK];

    const int t = threadIdx.x;
    const int wid = t >> 6, lane = t & 63;
    const int m0 = blockIdx.x * BM, n0 = blockIdx.y * BN;
    const int wrow = (wid >> 1) * (BM / 2);
    const int wcol = (wid & 1) * (BN / 2);
    const int lr = lane & 15, lk = (lane >> 4) * 8;

    f32x4 acc[MF][NF];
#pragma unroll
    for (int m = 0; m < MF; ++m)
#pragma unroll
        for (int n = 0; n < NF; ++n) acc[m][n] = (f32x4){0.f, 0.f, 0.f, 0.f};

    const unsigned short* Ag = A + (size_t)m0 * K;
    const unsigned short* Wg = W + (size_t)n0 * K;

#define G_STAGE(k0_, buf_)                                                        \
    do {                                                                          \
        _Pragma("unroll")                                                         \
        for (int i = 0; i < BM / 32; ++i) {                                       \
            const int e = (i * 256 + wid * 64 + lane) * 8;                        \
            gload_lds16(Ag + (size_t)(e >> 6) * K + (k0_) + (e & 63),             \
                        &As[buf_][(size_t)(i * 256 + wid * 64) * 8]);             \
        }                                                                         \
        _Pragma("unroll")                                                         \
        for (int i = 0; i < BN / 32; ++i) {                                       \
            const int e = (i * 256 + wid * 64 + lane) * 8;                        \
            gload_lds16(Wg + (size_t)(e >> 6) * K + (k0_) + (e & 63),             \
                        &Bs[buf_][(size_t)(i * 256 + wid * 64) * 8]);             \
        }                                                                         \
    } while (0)

    const int nk = K / BK;
    G_STAGE(0, 0);
    __syncthreads();

    for (int ki = 0; ki < nk; ++ki) {
        const int cur = ki & 1;
        if (ki + 1 < nk) G_STAGE((ki + 1) * BK, cur ^ 1);

#pragma unroll
        for (int kk = 0; kk < BK; kk += 32) {
            bf16x8 af[MF], bf[NF];
#pragma unroll
            for (int m = 0; m < MF; ++m)
                af[m] = *(const bf16x8*)&As[cur][(wrow + m * 16 + lr) * BK + kk + lk];
#pragma unroll
            for (int n = 0; n < NF; ++n)
                bf[n] = *(const bf16x8*)&Bs[cur][(wcol + n * 16 + lr) * BK + kk + lk];
#pragma unroll
            for (int m = 0; m < MF; ++m)
#pragma unroll
                for (int n = 0; n < NF; ++n)
                    acc[m][n] = __builtin_amdgcn_mfma_f32_16x16x32_bf16(af[m], bf[n], acc[m][n], 0, 0, 0);
        }
        __syncthreads();
    }
#undef G_STAGE

    const int orow0 = m0 + wrow + (lane >> 4) * 4;
    const int ocol0 = n0 + wcol + lr;
#pragma unroll
    for (int m = 0; m < MF; ++m)
#pragma unroll
        for (int n = 0; n < NF; ++n) {
            if (OUTMODE == 2) {
                const int nc = ocol0 + n * 16;
                const int mrow = orow0 + m * 16;
                unsigned short* dst = (unsigned short*)Cout
                    + (size_t)((mrow >> 11) * 16 + (nc >> 6)) * (64 * 2048)
                    + (size_t)(nc & 63) * 2048 + (mrow & 2047);
                ushort4v pv;
#pragma unroll
                for (int i = 0; i < 4; ++i) pv[i] = f2b(acc[m][n][i]);
                *(ushort4v*)dst = pv;
            } else {
#pragma unroll
                for (int i = 0; i < 4; ++i) {
                    const size_t idx = (size_t)(orow0 + m * 16 + i) * N + ocol0 + n * 16;
                    if (OUTMODE == 1) ((unsigned short*)Cout)[idx] = f2b(acc[m][n][i]);
                    else              ((float*)Cout)[idx] = acc[m][n][i];
                }
            }
        }
}

// ------- split-bf16 GEMM (qk projection), 2-phase dbuf, BM=BN=64 -------
__global__ __launch_bounds__(256) void gemm_split(const unsigned short* __restrict__ Ah,
                                                  const unsigned short* __restrict__ Al,
                                                  const unsigned short* __restrict__ Wh,
                                                  const unsigned short* __restrict__ Wl,
                                                  float* __restrict__ C,
                                                  int M, int N, int K) {
    constexpr int BM = 64, BN = 64, BK = 64;
    constexpr int MF = 2, NF = 2;
    __shared__ __align__(16) unsigned short Ahs[2][BM * BK];
    __shared__ __align__(16) unsigned short Als[2][BM * BK];
    __shared__ __align__(16) unsigned short Bhs[2][BN * BK];
    __shared__ __align__(16) unsigned short Bls[2][BN * BK];

    const int t = threadIdx.x;
    const int wid = t >> 6, lane = t & 63;
    const int m0 = blockIdx.x * BM, n0 = blockIdx.y * BN;
    const int wrow = (wid >> 1) * 32;
    const int wcol = (wid & 1) * 32;
    const int lr = lane & 15, lk = (lane >> 4) * 8;

    f32x4 acc[MF][NF];
#pragma unroll
    for (int m = 0; m < MF; ++m)
#pragma unroll
        for (int n = 0; n < NF; ++n) acc[m][n] = (f32x4){0.f, 0.f, 0.f, 0.f};

    const unsigned short* Ahg = Ah + (size_t)m0 * K;
    const unsigned short* Alg = Al + (size_t)m0 * K;
    const unsigned short* Whg = Wh + (size_t)n0 * K;
    const unsigned short* Wlg = Wl + (size_t)n0 * K;

#define S_STAGE(k0_, buf_)                                                        \
    do {                                                                          \
        _Pragma("unroll")                                                         \
        for (int i = 0; i < 2; ++i) {                                             \
            const int e = (i * 256 + wid * 64 + lane) * 8;                        \
            const size_t go = (size_t)(e >> 6) * K + (k0_) + (e & 63);            \
            const size_t lo = (size_t)(i * 256 + wid * 64) * 8;                   \
            gload_lds16(Ahg + go, &Ahs[buf_][lo]);                                \
            gload_lds16(Alg + go, &Als[buf_][lo]);                                \
            gload_lds16(Whg + go, &Bhs[buf_][lo]);                                \
            gload_lds16(Wlg + go, &Bls[buf_][lo]);                                \
        }                                                                         \
    } while (0)

    const int nk = K / BK;
    S_STAGE(0, 0);
    __syncthreads();

    for (int ki = 0; ki < nk; ++ki) {
        const int cur = ki & 1;
        if (ki + 1 < nk) S_STAGE((ki + 1) * BK, cur ^ 1);

#pragma unroll
        for (int kk = 0; kk < BK; kk += 32) {
            bf16x8 afh[MF], afl[MF], bfh[NF], bfl[NF];
#pragma unroll
            for (int m = 0; m < MF; ++m) {
                afh[m] = *(const bf16x8*)&Ahs[cur][(wrow + m * 16 + lr) * BK + kk + lk];
                afl[m] = *(const bf16x8*)&Als[cur][(wrow + m * 16 + lr) * BK + kk + lk];
            }
#pragma unroll
            for (int n = 0; n < NF; ++n) {
                bfh[n] = *(const bf16x8*)&Bhs[cur][(wcol + n * 16 + lr) * BK + kk + lk];
                bfl[n] = *(const bf16x8*)&Bls[cur][(wcol + n * 16 + lr) * BK + kk + lk];
            }
#pragma unroll
            for (int m = 0; m < MF; ++m)
#pragma unroll
                for (int n = 0; n < NF; ++n) {
                    acc[m][n] = __builtin_amdgcn_mfma_f32_16x16x32_bf16(afh[m], bfh[n], acc[m][n], 0, 0, 0);
                    acc[m][n] = __builtin_amdgcn_mfma_f32_16x16x32_bf16(afh[m], bfl[n], acc[m][n], 0, 0, 0);
                    acc[m][n] = __builtin_amdgcn_mfma_f32_16x16x32_bf16(afl[m], bfh[n], acc[m][n], 0, 0, 0);
                }
        }
        __syncthreads();
    }
#undef S_STAGE

    const int orow0 = m0 + wrow + (lane >> 4) * 4;
    const int ocol0 = n0 + wcol + lr;
#pragma unroll
    for (int m = 0; m < MF; ++m)
#pragma unroll
        for (int n = 0; n < NF; ++n)
#pragma unroll
            for (int i = 0; i < 4; ++i)
                C[(size_t)(orow0 + m * 16 + i) * N + ocol0 + n * 16] = acc[m][n][i];
}

// ---------------- f32 -> bf16 casts ----------------
__global__ __launch_bounds__(256) void cast_bf16(const float* __restrict__ in,
                                                 unsigned short* __restrict__ out, int n) {
    const int i = (blockIdx.x * 256 + threadIdx.x) * 8;
    if (i >= n) return;
    float4 a = *(const float4*)(in + i);
    float4 b = *(const float4*)(in + i + 4);
    ushort8 o;
    o[0] = f2b(a.x); o[1] = f2b(a.y); o[2] = f2b(a.z); o[3] = f2b(a.w);
    o[4] = f2b(b.x); o[5] = f2b(b.y); o[6] = f2b(b.z); o[7] = f2b(b.w);
    *(ushort8*)(out + i) = o;
}

__global__ __launch_bounds__(256) void cast_split(const float* __restrict__ in,
                                                  unsigned short* __restrict__ hi,
                                                  unsigned short* __restrict__ lo, int n) {
    const int i = (blockIdx.x * 256 + threadIdx.x) * 8;
    if (i >= n) return;
    float4 a = *(const float4*)(in + i);
    float4 b = *(const float4*)(in + i + 4);
    float xv[8] = {a.x, a.y, a.z, a.w, b.x, b.y, b.z, b.w};
    ushort8 oh, ol;
#pragma unroll
    for (int e = 0; e < 8; ++e) {
        const unsigned short h = f2b(xv[e]);
        oh[e] = h;
        ol[e] = f2b(xv[e] - b2f(h));
    }
    *(ushort8*)(hi + i) = oh;
    *(ushort8*)(lo + i) = ol;
}

// ------- feature map: qk_raw f32 -> q/k split hi|lo bf16 [bh][l][32] -------
__global__ __launch_bounds__(256) void ln_featuremap(const float* __restrict__ qk,
                                                     const float* __restrict__ gamma,
                                                     const float* __restrict__ beta,
                                                     unsigned short* __restrict__ qhl,
                                                     unsigned short* __restrict__ khl) {
    const int gid = blockIdx.x * 256 + threadIdx.x;
    const int idx = gid & 31;
    const int m = gid >> 5;
    const int b = m >> 11, l = m & 2047;
    const int h = idx & 15;
    const float scale = (idx < 16) ? 0.25f : 1.0f;
    const float* p = qk + (size_t)gid * 16;

    float xv[16];
    float4 v0 = *(const float4*)(p + 0);
    float4 v1 = *(const float4*)(p + 4);
    float4 v2 = *(const float4*)(p + 8);
    float4 v3 = *(const float4*)(p + 12);
    xv[0]=v0.x; xv[1]=v0.y; xv[2]=v0.z; xv[3]=v0.w;
    xv[4]=v1.x; xv[5]=v1.y; xv[6]=v1.z; xv[7]=v1.w;
    xv[8]=v2.x; xv[9]=v2.y; xv[10]=v2.z; xv[11]=v2.w;
    xv[12]=v3.x; xv[13]=v3.y; xv[14]=v3.z; xv[15]=v3.w;

    float mu = 0.f;
#pragma unroll
    for (int f = 0; f < 16; ++f) mu += xv[f];
    mu *= 0.0625f;
    float var = 0.f;
#pragma unroll
    for (int f = 0; f < 16; ++f) { float d = xv[f] - mu; var = fmaf(d, d, var); }
    var *= 0.0625f;
    const float rs = rsqrtf(var + 1e-5f);

    ushort8 hi0, hi1, lo0, lo1;
#pragma unroll
    for (int f = 0; f < 16; ++f) {
        const float v = ((xv[f] - mu) * rs * gamma[f] + beta[f]) * scale;
        const unsigned short hb = f2b(v);
        const unsigned short lb = f2b(v - b2f(hb));
        if (f < 8) { hi0[f] = hb; lo0[f] = lb; }
        else       { hi1[f - 8] = hb; lo1[f - 8] = lb; }
    }
    unsigned short* dst = ((idx < 16) ? qhl : khl)
        + ((size_t)(b * 16 + h) * 2048 + l) * 32;
    *(ushort8*)(dst + 0)  = hi0;
    *(ushort8*)(dst + 8)  = hi1;
    *(ushort8*)(dst + 16) = lo0;
    *(ushort8*)(dst + 24) = lo1;
}

// ------- causal (q.k)^2 attention: 32x32 MFMA, P-in-register via permlane -------
// grid (32 bh, 8 x). 256 thr = 4 waves; wave w owns q-tile {x,15-x,16+x,31-x}[w]
// (64 q-rows = 2x32 subtiles). qhl/khl: [bh][l][32]=[hi16|lo16]; vT: [bh][64][2048].
// LDS: K tile [og4][64][8], V tile [og8][64][8], triple-buffered; NO P in LDS.
__global__ __launch_bounds__(256) void rebased_attn(const unsigned short* __restrict__ qhl_g,
                                                    const unsigned short* __restrict__ khl_g,
                                                    const unsigned short* __restrict__ vT,
                                                    unsigned short* __restrict__ o) {
    const int bh = blockIdx.x;
    const int x  = blockIdx.y;
    const int bb = bh >> 4;
    const int t = threadIdx.x;
    const int wid = t >> 6, lane = t & 63;
    const int lq = lane & 31, lh = lane >> 5;
    const int qt = (wid == 0) ? x : (wid == 1) ? (15 - x) : (wid == 2) ? (16 + x) : (31 - x);
    const int qtmax = 31 - x;

    __shared__ __align__(16) unsigned short khl[3][4 * 64 * 8];   // [og][row][8] x3
    __shared__ __align__(16) unsigned short vsl[3][8 * 64 * 8];   // [og'][d][8] x3
    __shared__ float zbuf[4][2][32];

    const unsigned short* qg  = qhl_g + (size_t)bh * 2048 * 32;
    const unsigned short* kg  = khl_g + (size_t)bh * 2048 * 32;
    const unsigned short* vbh = vT + (size_t)bh * 64 * 2048;
    unsigned short*       obh = o  + (size_t)bb * 2048 * 1024 + (bh & 15) * 64;

    const f32x16 zc16 = (f32x16)(0.f);

    // Q B-frags, in VGPRs for the whole kernel: row = qt*64+qs*32+lq, oct lh
    bf16x8 bqh[2], bql[2];
#pragma unroll
    for (int qs = 0; qs < 2; ++qs) {
        const unsigned short* qr = qg + (size_t)(qt * 64 + qs * 32 + lq) * 32;
        bqh[qs] = *(const bf16x8*)&qr[lh * 8];
        bql[qs] = *(const bf16x8*)&qr[16 + lh * 8];
    }

    // staging: 12 chunks over 4 waves, 3 loads/wave/step
#define STAGE_KV(kt_, buf_)                                                            \
    do {                                                                               \
        gload_lds16(kg + ((size_t)((kt_) << 6) + lane) * 32 + wid * 8,                 \
                    &khl[buf_][wid * 512]);                                            \
        gload_lds16(vbh + (size_t)lane * 2048 + ((kt_) << 6) + (2 * wid) * 8,          \
                    &vsl[buf_][(2 * wid) * 512]);                                      \
        gload_lds16(vbh + (size_t)lane * 2048 + ((kt_) << 6) + (2 * wid + 1) * 8,      \
                    &vsl[buf_][(2 * wid + 1) * 512]);                                  \
    } while (0)

    STAGE_KV(0, 0);
    STAGE_KV(1, 1);
    asm volatile("s_waitcnt vmcnt(3)" ::: "memory");
    __builtin_amdgcn_s_barrier();

    f32x16 oacc[2][2];
#pragma unroll
    for (int qs = 0; qs < 2; ++qs)
#pragma unroll
        for (int dt = 0; dt < 2; ++dt) oacc[qs][dt] = zc16;
    float zl[2] = {0.f, 0.f};

    for (int kt = 0; kt <= qtmax; ++kt) {
        const int cur = kt % 3;
        const bool pf = (kt + 2 <= qtmax);
        if (pf) STAGE_KV(kt + 2, (kt + 2) % 3);

        if (kt <= qt) {   // wave-uniform activity
            // phase 1: S^T = K x Q via 3-term hi/lo 32x32x16 MFMAs
            f32x16 D[2][2];
#pragma unroll
            for (int st = 0; st < 2; ++st) {
                const bf16x8 kh = *(const bf16x8*)&khl[cur][((lh    ) * 64 + st * 32 + lq) * 8];
                const bf16x8 kl = *(const bf16x8*)&khl[cur][((2 + lh) * 64 + st * 32 + lq) * 8];
#pragma unroll
                for (int qs = 0; qs < 2; ++qs) {
                    f32x16 a = __builtin_amdgcn_mfma_f32_32x32x16_bf16(kh, bql[qs], zc16, 0, 0, 0);
                    a = __builtin_amdgcn_mfma_f32_32x32x16_bf16(kl, bqh[qs], a, 0, 0, 0);
                    a = __builtin_amdgcn_mfma_f32_32x32x16_bf16(kh, bqh[qs], a, 0, 0, 0);
                    D[st][qs] = a;
                }
            }
            // square + causal mask (diag only) + z accum; D <- P (f32)
            const bool diag = (kt == qt);
#pragma unroll
            for (int st = 0; st < 2; ++st)
#pragma unroll
                for (int qs = 0; qs < 2; ++qs)
#pragma unroll
                    for (int r = 0; r < 16; ++r) {
                        const float v = D[st][qs][r];
                        float s2 = v * v;
                        if (diag) {
                            const int kr = st * 32 + (r & 3) + 8 * (r >> 2) + 4 * lh;
                            const int qr = qs * 32 + lq;
                            s2 = (kr <= qr) ? s2 : 0.f;
                        }
                        zl[qs] += s2;
                        D[st][qs][r] = s2;
                    }
            // phase 2: O += P @ V; P A-frags assembled in-register
#pragma unroll
            for (int ks = 0; ks < 4; ++ks) {
                const int st = ks >> 1, b = 8 * (ks & 1);
                const bf16x8 vb0 = *(const bf16x8*)&vsl[cur][((2 * ks + lh) * 64 + 0 * 32 + lq) * 8];
                const bf16x8 vb1 = *(const bf16x8*)&vsl[cur][((2 * ks + lh) * 64 + 1 * 32 + lq) * 8];
#pragma unroll
                for (int qs = 0; qs < 2; ++qs) {
                    unsigned u0 = pk2(D[st][qs][b + 0], D[st][qs][b + 1]);
                    unsigned u1 = pk2(D[st][qs][b + 2], D[st][qs][b + 3]);
                    unsigned v0 = pk2(D[st][qs][b + 4], D[st][qs][b + 5]);
                    unsigned v1 = pk2(D[st][qs][b + 6], D[st][qs][b + 7]);
                    // u' = [u_lo, v_lo], v' = [u_hi, v_hi]  (vdst.hi <-> vsrc.lo)
                    asm("v_permlane32_swap_b32 %0, %1" : "+v"(u0), "+v"(v0));
                    asm("v_permlane32_swap_b32 %0, %1" : "+v"(u1), "+v"(v1));
                    uint4v pw; pw[0] = u0; pw[1] = u1; pw[2] = v0; pw[3] = v1;
                    const bf16x8 pa = __builtin_bit_cast(bf16x8, pw);
                    oacc[qs][0] = __builtin_amdgcn_mfma_f32_32x32x16_bf16(pa, vb0, oacc[qs][0], 0, 0, 0);
                    oacc[qs][1] = __builtin_amdgcn_mfma_f32_32x32x16_bf16(pa, vb1, oacc[qs][1], 0, 0, 0);
                }
            }
        }

        if (pf) asm volatile("s_waitcnt vmcnt(3)" ::: "memory");
        else    asm volatile("s_waitcnt vmcnt(0)" ::: "memory");
        __builtin_amdgcn_s_barrier();
    }
#undef STAGE_KV

    // z finalize: q = lq within each subtile; halves lh=0/1 hold partial sums
#pragma unroll
    for (int qs = 0; qs < 2; ++qs) {
        const float z = zl[qs] + __shfl_xor(zl[qs], 32);
        if (lh == 0) zbuf[wid][qs][lq] = 1.f / (z + 1e-5f);
    }
    // wave-local zbuf (written+read by same wave; compiler orders lgkmcnt)
#pragma unroll
    for (int qs = 0; qs < 2; ++qs)
#pragma unroll
        for (int dt = 0; dt < 2; ++dt)
#pragma unroll
            for (int r = 0; r < 16; ++r) {
                const int qr = (r & 3) + 8 * (r >> 2) + 4 * lh;
                const float zi = zbuf[wid][qs][qr];
                obh[(size_t)(qt * 64 + qs * 32 + qr) * 1024 + dt * 32 + lq] =
                    f2b(oacc[qs][dt][r] * zi);
            }
}

extern "C" void kernel_launch(void* const* d_in, const int* in_sizes, int n_in,
                              void* d_out, int out_size, void* d_ws, size_t ws_size,
                              hipStream_t stream) {
    const float* x     = (const float*)d_in[0];
    const float* Wq    = (const float*)d_in[1];
    const float* Wk    = (const float*)d_in[2];
    const float* Wv    = (const float*)d_in[3];
    const float* Wo    = (const float*)d_in[4];
    const float* gamma = (const float*)d_in[5];
    const float* beta  = (const float*)d_in[6];
    float* out = (float*)d_out;
    (void)in_sizes; (void)n_in; (void)out_size; (void)ws_size;

    char* w = (char*)d_ws;
    float*          qk_raw = (float*)w;                                   // 8 MB @ 0
    unsigned short* vTb    = (unsigned short*)(w + (8u  << 20));          // 8 MB [bh][64][2048]
    unsigned short* ob     = (unsigned short*)(w + (16u << 20));          // 8 MB
    unsigned short* xh     = (unsigned short*)(w + (24u << 20));          // 8 MB (dead after gemms)
    unsigned short* xl     = (unsigned short*)(w + (32u << 20));          // 8 MB (dead after gemm_split)
    unsigned short* qhl_g  = (unsigned short*)(w + (24u << 20));          // 4 MB (overlays dead xh)
    unsigned short* khl_g  = (unsigned short*)(w + (28u << 20));          // 4 MB (overlays dead xh)
    unsigned short* wqkh   = (unsigned short*)(w + (40u << 20));          // 1 MB
    unsigned short* wqkl   = (unsigned short*)(w + (41u << 20));          // 1 MB
    unsigned short* wvb    = (unsigned short*)(w + (42u << 20));          // 2 MB
    unsigned short* wob    = (unsigned short*)(w + (44u << 20));          // 2 MB

    cast_split<<<2048, 256, 0, stream>>>(x,  xh, xl, 4096 * 1024);
    cast_split<<<128,  256, 0, stream>>>(Wq, wqkh, wqkl, 256 * 1024);
    cast_split<<<128,  256, 0, stream>>>(Wk, wqkh + 256 * 1024, wqkl + 256 * 1024, 256 * 1024);
    cast_bf16 <<<512,  256, 0, stream>>>(Wv, wvb, 1024 * 1024);
    cast_bf16 <<<512,  256, 0, stream>>>(Wo, wob, 1024 * 1024);

    // qk projection (split-bf16, ~fp32): [4096][512] f32
    gemm_split<<<dim3(64, 8), 256, 0, stream>>>(xh, xl, wqkh, wqkl, qk_raw, 4096, 512, 1024);
    // v projection -> transposed bf16 vT[bh][d][l]
    gemm_mfma<64, 64, 2><<<dim3(64, 16), 256, 0, stream>>>(xh, wvb, vTb, 4096, 1024, 1024);
    // feature map -> q/k hi|lo bf16 [bh][l][32]
    ln_featuremap<<<512, 256, 0, stream>>>(qk_raw, gamma, beta, qhl_g, khl_g);
    // attention -> bf16 ob; 4-wave quad blocks, 32x32 MFMA, P in registers
    rebased_attn<<<dim3(32, 8), 256, 0, stream>>>(qhl_g, khl_g, vTb, ob);
    // output projection -> f32 out
    gemm_mfma<64, 64, 0><<<dim3(64, 16), 256, 0, stream>>>(ob, wob, out, 4096, 1024, 1024);
}

// Round 13
// 121.539 us; speedup vs baseline: 1.2348x; 1.2348x over previous
//
#include <hip/hip_runtime.h>
#include <cstddef>
#include <cstdint>

// ReBased linear attention, round 13.
// r12 fail root cause: diagonal causal mask lost the subtile offset --
// `kr <= lq` instead of `kr <= qs*32 + lq` (wave owns q-subtile qs). One-line
// fix; r12 structure otherwise unchanged (8-wave blocks, 2 waves/SIMD,
// 32x32 MFMA, P-in-register via permlane32_swap -- verified r11).

typedef __attribute__((ext_vector_type(8)))  __bf16 bf16x8;
typedef __attribute__((ext_vector_type(2)))  __bf16 bf16x2;
typedef __attribute__((ext_vector_type(4)))  float  f32x4;
typedef __attribute__((ext_vector_type(16))) float  f32x16;
typedef __attribute__((ext_vector_type(8)))  unsigned short ushort8;
typedef __attribute__((ext_vector_type(4)))  unsigned short ushort4v;
typedef __attribute__((ext_vector_type(4)))  unsigned int   uint4v;

__device__ __forceinline__ unsigned short f2b(float f) {
    union { float f; unsigned u; } v; v.f = f;
    unsigned r = v.u + 0x7FFFu + ((v.u >> 16) & 1u);   // RNE
    return (unsigned short)(r >> 16);
}
__device__ __forceinline__ float b2f(unsigned short b) {
    union { unsigned u; float f; } v; v.u = ((unsigned)b) << 16;
    return v.f;
}
__device__ __forceinline__ unsigned pk2(float a, float b) {
    bf16x2 p; p[0] = (__bf16)a; p[1] = (__bf16)b;
    return __builtin_bit_cast(unsigned, p);
}

typedef const __attribute__((address_space(1))) void* gas_ptr;
typedef __attribute__((address_space(3))) void* las_ptr;

__device__ __forceinline__ void gload_lds16(const unsigned short* g, unsigned short* l) {
    // 16B/lane; LDS dest = wave-uniform base + lane*16
    __builtin_amdgcn_global_load_lds((gas_ptr)g, (las_ptr)l, 16, 0, 0);
}

// ---------------- bf16 MFMA GEMM, 2-phase dbuf: C = A @ W^T ----------------
template <int BM, int BN, int OUTMODE>
__global__ __launch_bounds__(256) void gemm_mfma(const unsigned short* __restrict__ A,
                                                 const unsigned short* __restrict__ W,
                                                 void* __restrict__ Cout,
                                                 int M, int N, int K) {
    constexpr int BK = 64;
    constexpr int MF = BM / 32;
    constexpr int NF = BN / 32;
    __shared__ __align__(16) unsigned short As[2][BM * BK];
    __shared__ __align__(16) unsigned short Bs[2][BN * BK];

    const int t = threadIdx.x;
    const int wid = t >> 6, lane = t & 63;
    const int m0 = blockIdx.x * BM, n0 = blockIdx.y * BN;
    const int wrow = (wid >> 1) * (BM / 2);
    const int wcol = (wid & 1) * (BN / 2);
    const int lr = lane & 15, lk = (lane >> 4) * 8;

    f32x4 acc[MF][NF];
#pragma unroll
    for (int m = 0; m < MF; ++m)
#pragma unroll
        for (int n = 0; n < NF; ++n) acc[m][n] = (f32x4){0.f, 0.f, 0.f, 0.f};

    const unsigned short* Ag = A + (size_t)m0 * K;
    const unsigned short* Wg = W + (size_t)n0 * K;

#define G_STAGE(k0_, buf_)                                                        \
    do {                                                                          \
        _Pragma("unroll")                                                         \
        for (int i = 0; i < BM / 32; ++i) {                                       \
            const int e = (i * 256 + wid * 64 + lane) * 8;                        \
            gload_lds16(Ag + (size_t)(e >> 6) * K + (k0_) + (e & 63),             \
                        &As[buf_][(size_t)(i * 256 + wid * 64) * 8]);             \
        }                                                                         \
        _Pragma("unroll")                                                         \
        for (int i = 0; i < BN / 32; ++i) {                                       \
            const int e = (i * 256 + wid * 64 + lane) * 8;                        \
            gload_lds16(Wg + (size_t)(e >> 6) * K + (k0_) + (e & 63),             \
                        &Bs[buf_][(size_t)(i * 256 + wid * 64) * 8]);             \
        }                                                                         \
    } while (0)

    const int nk = K / BK;
    G_STAGE(0, 0);
    __syncthreads();

    for (int ki = 0; ki < nk; ++ki) {
        const int cur = ki & 1;
        if (ki + 1 < nk) G_STAGE((ki + 1) * BK, cur ^ 1);

#pragma unroll
        for (int kk = 0; kk < BK; kk += 32) {
            bf16x8 af[MF], bf[NF];
#pragma unroll
            for (int m = 0; m < MF; ++m)
                af[m] = *(const bf16x8*)&As[cur][(wrow + m * 16 + lr) * BK + kk + lk];
#pragma unroll
            for (int n = 0; n < NF; ++n)
                bf[n] = *(const bf16x8*)&Bs[cur][(wcol + n * 16 + lr) * BK + kk + lk];
#pragma unroll
            for (int m = 0; m < MF; ++m)
#pragma unroll
                for (int n = 0; n < NF; ++n)
                    acc[m][n] = __builtin_amdgcn_mfma_f32_16x16x32_bf16(af[m], bf[n], acc[m][n], 0, 0, 0);
        }
        __syncthreads();
    }
#undef G_STAGE

    const int orow0 = m0 + wrow + (lane >> 4) * 4;
    const int ocol0 = n0 + wcol + lr;
#pragma unroll
    for (int m = 0; m < MF; ++m)
#pragma unroll
        for (int n = 0; n < NF; ++n) {
            if (OUTMODE == 2) {
                const int nc = ocol0 + n * 16;
                const int mrow = orow0 + m * 16;
                unsigned short* dst = (unsigned short*)Cout
                    + (size_t)((mrow >> 11) * 16 + (nc >> 6)) * (64 * 2048)
                    + (size_t)(nc & 63) * 2048 + (mrow & 2047);
                ushort4v pv;
#pragma unroll
                for (int i = 0; i < 4; ++i) pv[i] = f2b(acc[m][n][i]);
                *(ushort4v*)dst = pv;
            } else {
#pragma unroll
                for (int i = 0; i < 4; ++i) {
                    const size_t idx = (size_t)(orow0 + m * 16 + i) * N + ocol0 + n * 16;
                    if (OUTMODE == 1) ((unsigned short*)Cout)[idx] = f2b(acc[m][n][i]);
                    else              ((float*)Cout)[idx] = acc[m][n][i];
                }
            }
        }
}

// ------- split-bf16 GEMM (qk projection), 2-phase dbuf, BM=BN=64 -------
__global__ __launch_bounds__(256) void gemm_split(const unsigned short* __restrict__ Ah,
                                                  const unsigned short* __restrict__ Al,
                                                  const unsigned short* __restrict__ Wh,
                                                  const unsigned short* __restrict__ Wl,
                                                  float* __restrict__ C,
                                                  int M, int N, int K) {
    constexpr int BM = 64, BN = 64, BK = 64;
    constexpr int MF = 2, NF = 2;
    __shared__ __align__(16) unsigned short Ahs[2][BM * BK];
    __shared__ __align__(16) unsigned short Als[2][BM * BK];
    __shared__ __align__(16) unsigned short Bhs[2][BN * BK];
    __shared__ __align__(16) unsigned short Bls[2][BN * BK];

    const int t = threadIdx.x;
    const int wid = t >> 6, lane = t & 63;
    const int m0 = blockIdx.x * BM, n0 = blockIdx.y * BN;
    const int wrow = (wid >> 1) * 32;
    const int wcol = (wid & 1) * 32;
    const int lr = lane & 15, lk = (lane >> 4) * 8;

    f32x4 acc[MF][NF];
#pragma unroll
    for (int m = 0; m < MF; ++m)
#pragma unroll
        for (int n = 0; n < NF; ++n) acc[m][n] = (f32x4){0.f, 0.f, 0.f, 0.f};

    const unsigned short* Ahg = Ah + (size_t)m0 * K;
    const unsigned short* Alg = Al + (size_t)m0 * K;
    const unsigned short* Whg = Wh + (size_t)n0 * K;
    const unsigned short* Wlg = Wl + (size_t)n0 * K;

#define S_STAGE(k0_, buf_)                                                        \
    do {                                                                          \
        _Pragma("unroll")                                                         \
        for (int i = 0; i < 2; ++i) {                                             \
            const int e = (i * 256 + wid * 64 + lane) * 8;                        \
            const size_t go = (size_t)(e >> 6) * K + (k0_) + (e & 63);            \
            const size_t lo = (size_t)(i * 256 + wid * 64) * 8;                   \
            gload_lds16(Ahg + go, &Ahs[buf_][lo]);                                \
            gload_lds16(Alg + go, &Als[buf_][lo]);                                \
            gload_lds16(Whg + go, &Bhs[buf_][lo]);                                \
            gload_lds16(Wlg + go, &Bls[buf_][lo]);                                \
        }                                                                         \
    } while (0)

    const int nk = K / BK;
    S_STAGE(0, 0);
    __syncthreads();

    for (int ki = 0; ki < nk; ++ki) {
        const int cur = ki & 1;
        if (ki + 1 < nk) S_STAGE((ki + 1) * BK, cur ^ 1);

#pragma unroll
        for (int kk = 0; kk < BK; kk += 32) {
            bf16x8 afh[MF], afl[MF], bfh[NF], bfl[NF];
#pragma unroll
            for (int m = 0; m < MF; ++m) {
                afh[m] = *(const bf16x8*)&Ahs[cur][(wrow + m * 16 + lr) * BK + kk + lk];
                afl[m] = *(const bf16x8*)&Als[cur][(wrow + m * 16 + lr) * BK + kk + lk];
            }
#pragma unroll
            for (int n = 0; n < NF; ++n) {
                bfh[n] = *(const bf16x8*)&Bhs[cur][(wcol + n * 16 + lr) * BK + kk + lk];
                bfl[n] = *(const bf16x8*)&Bls[cur][(wcol + n * 16 + lr) * BK + kk + lk];
            }
#pragma unroll
            for (int m = 0; m < MF; ++m)
#pragma unroll
                for (int n = 0; n < NF; ++n) {
                    acc[m][n] = __builtin_amdgcn_mfma_f32_16x16x32_bf16(afh[m], bfh[n], acc[m][n], 0, 0, 0);
                    acc[m][n] = __builtin_amdgcn_mfma_f32_16x16x32_bf16(afh[m], bfl[n], acc[m][n], 0, 0, 0);
                    acc[m][n] = __builtin_amdgcn_mfma_f32_16x16x32_bf16(afl[m], bfh[n], acc[m][n], 0, 0, 0);
                }
        }
        __syncthreads();
    }
#undef S_STAGE

    const int orow0 = m0 + wrow + (lane >> 4) * 4;
    const int ocol0 = n0 + wcol + lr;
#pragma unroll
    for (int m = 0; m < MF; ++m)
#pragma unroll
        for (int n = 0; n < NF; ++n)
#pragma unroll
            for (int i = 0; i < 4; ++i)
                C[(size_t)(orow0 + m * 16 + i) * N + ocol0 + n * 16] = acc[m][n][i];
}

// ---------------- f32 -> bf16 casts ----------------
__global__ __launch_bounds__(256) void cast_bf16(const float* __restrict__ in,
                                                 unsigned short* __restrict__ out, int n) {
    const int i = (blockIdx.x * 256 + threadIdx.x) * 8;
    if (i >= n) return;
    float4 a = *(const float4*)(in + i);
    float4 b = *(const float4*)(in + i + 4);
    ushort8 o;
    o[0] = f2b(a.x); o[1] = f2b(a.y); o[2] = f2b(a.z); o[3] = f2b(a.w);
    o[4] = f2b(b.x); o[5] = f2b(b.y); o[6] = f2b(b.z); o[7] = f2b(b.w);
    *(ushort8*)(out + i) = o;
}

__global__ __launch_bounds__(256) void cast_split(const float* __restrict__ in,
                                                  unsigned short* __restrict__ hi,
                                                  unsigned short* __restrict__ lo, int n) {
    const int i = (blockIdx.x * 256 + threadIdx.x) * 8;
    if (i >= n) return;
    float4 a = *(const float4*)(in + i);
    float4 b = *(const float4*)(in + i + 4);
    float xv[8] = {a.x, a.y, a.z, a.w, b.x, b.y, b.z, b.w};
    ushort8 oh, ol;
#pragma unroll
    for (int e = 0; e < 8; ++e) {
        const unsigned short h = f2b(xv[e]);
        oh[e] = h;
        ol[e] = f2b(xv[e] - b2f(h));
    }
    *(ushort8*)(hi + i) = oh;
    *(ushort8*)(lo + i) = ol;
}

// ------- feature map: qk_raw f32 -> q/k split hi|lo bf16 [bh][l][32] -------
__global__ __launch_bounds__(256) void ln_featuremap(const float* __restrict__ qk,
                                                     const float* __restrict__ gamma,
                                                     const float* __restrict__ beta,
                                                     unsigned short* __restrict__ qhl,
                                                     unsigned short* __restrict__ khl) {
    const int gid = blockIdx.x * 256 + threadIdx.x;
    const int idx = gid & 31;
    const int m = gid >> 5;
    const int b = m >> 11, l = m & 2047;
    const int h = idx & 15;
    const float scale = (idx < 16) ? 0.25f : 1.0f;
    const float* p = qk + (size_t)gid * 16;

    float xv[16];
    float4 v0 = *(const float4*)(p + 0);
    float4 v1 = *(const float4*)(p + 4);
    float4 v2 = *(const float4*)(p + 8);
    float4 v3 = *(const float4*)(p + 12);
    xv[0]=v0.x; xv[1]=v0.y; xv[2]=v0.z; xv[3]=v0.w;
    xv[4]=v1.x; xv[5]=v1.y; xv[6]=v1.z; xv[7]=v1.w;
    xv[8]=v2.x; xv[9]=v2.y; xv[10]=v2.z; xv[11]=v2.w;
    xv[12]=v3.x; xv[13]=v3.y; xv[14]=v3.z; xv[15]=v3.w;

    float mu = 0.f;
#pragma unroll
    for (int f = 0; f < 16; ++f) mu += xv[f];
    mu *= 0.0625f;
    float var = 0.f;
#pragma unroll
    for (int f = 0; f < 16; ++f) { float d = xv[f] - mu; var = fmaf(d, d, var); }
    var *= 0.0625f;
    const float rs = rsqrtf(var + 1e-5f);

    ushort8 hi0, hi1, lo0, lo1;
#pragma unroll
    for (int f = 0; f < 16; ++f) {
        const float v = ((xv[f] - mu) * rs * gamma[f] + beta[f]) * scale;
        const unsigned short hb = f2b(v);
        const unsigned short lb = f2b(v - b2f(hb));
        if (f < 8) { hi0[f] = hb; lo0[f] = lb; }
        else       { hi1[f - 8] = hb; lo1[f - 8] = lb; }
    }
    unsigned short* dst = ((idx < 16) ? qhl : khl)
        + ((size_t)(b * 16 + h) * 2048 + l) * 32;
    *(ushort8*)(dst + 0)  = hi0;
    *(ushort8*)(dst + 8)  = hi1;
    *(ushort8*)(dst + 16) = lo0;
    *(ushort8*)(dst + 24) = lo1;
}

// ------- causal (q.k)^2 attention: 32x32 MFMA, P-in-register, 8-wave blocks -------
// grid (32 bh, 8 x). 512 thr = 8 waves; wave w: q-tile quad[w>>1], subtile w&1
// (32 q-rows). qhl/khl: [bh][l][32]=[hi16|lo16]; vT: [bh][64][2048].
__global__ __launch_bounds__(512) void rebased_attn(const unsigned short* __restrict__ qhl_g,
                                                    const unsigned short* __restrict__ khl_g,
                                                    const unsigned short* __restrict__ vT,
                                                    unsigned short* __restrict__ o) {
    const int bh = blockIdx.x;
    const int x  = blockIdx.y;
    const int bb = bh >> 4;
    const int t = threadIdx.x;
    const int wid = t >> 6, lane = t & 63;
    const int lq = lane & 31, lh = lane >> 5;
    const int tq = wid >> 1, qs = wid & 1;
    const int qt = (tq == 0) ? x : (tq == 1) ? (15 - x) : (tq == 2) ? (16 + x) : (31 - x);
    const int qtmax = 31 - x;

    __shared__ __align__(16) unsigned short khl[3][4 * 64 * 8];   // [og][row][8] x3
    __shared__ __align__(16) unsigned short vsl[3][8 * 64 * 8];   // [og'][d][8] x3
    __shared__ float zbuf[8][32];

    const unsigned short* qg  = qhl_g + (size_t)bh * 2048 * 32;
    const unsigned short* kg  = khl_g + (size_t)bh * 2048 * 32;
    const unsigned short* vbh = vT + (size_t)bh * 64 * 2048;
    unsigned short*       obh = o  + (size_t)bb * 2048 * 1024 + (bh & 15) * 64;

    const f32x16 zc16 = (f32x16)(0.f);

    // Q B-frags in VGPRs: row = qt*64 + qs*32 + lq, octet lh (hi) / 2+lh (lo)
    const unsigned short* qr_ = qg + (size_t)(qt * 64 + qs * 32 + lq) * 32;
    const bf16x8 bqh = *(const bf16x8*)&qr_[lh * 8];
    const bf16x8 bql = *(const bf16x8*)&qr_[16 + lh * 8];

    // staging: K 4 chunks (waves 0-3), V 8 chunks (all waves)
#define STAGE_KV(kt_, buf_)                                                            \
    do {                                                                               \
        if (wid < 4)                                                                   \
            gload_lds16(kg + ((size_t)((kt_) << 6) + lane) * 32 + wid * 8,             \
                        &khl[buf_][wid * 512]);                                        \
        gload_lds16(vbh + (size_t)lane * 2048 + ((kt_) << 6) + wid * 8,                \
                    &vsl[buf_][wid * 512]);                                            \
    } while (0)

    STAGE_KV(0, 0);
    STAGE_KV(1, 1);
    if (wid < 4) asm volatile("s_waitcnt vmcnt(2)" ::: "memory");
    else         asm volatile("s_waitcnt vmcnt(1)" ::: "memory");
    __builtin_amdgcn_s_barrier();

    f32x16 oacc[2];
    oacc[0] = zc16; oacc[1] = zc16;
    float zl = 0.f;

    for (int kt = 0; kt <= qtmax; ++kt) {
        const int cur = kt % 3;
        const bool pf = (kt + 2 <= qtmax);
        if (pf) STAGE_KV(kt + 2, (kt + 2) % 3);

        if (kt <= qt) {   // wave-uniform activity
            // phase 1: S^T = K x Q via 3-term hi/lo 32x32x16 MFMAs
            f32x16 D[2];
#pragma unroll
            for (int st = 0; st < 2; ++st) {
                const bf16x8 kh = *(const bf16x8*)&khl[cur][((lh    ) * 64 + st * 32 + lq) * 8];
                const bf16x8 kl = *(const bf16x8*)&khl[cur][((2 + lh) * 64 + st * 32 + lq) * 8];
                f32x16 a = __builtin_amdgcn_mfma_f32_32x32x16_bf16(kh, bql, zc16, 0, 0, 0);
                a = __builtin_amdgcn_mfma_f32_32x32x16_bf16(kl, bqh, a, 0, 0, 0);
                a = __builtin_amdgcn_mfma_f32_32x32x16_bf16(kh, bqh, a, 0, 0, 0);
                D[st] = a;
            }
            // square + causal mask (diag only) + z accum
            const bool diag = (kt == qt);
#pragma unroll
            for (int st = 0; st < 2; ++st)
#pragma unroll
                for (int r = 0; r < 16; ++r) {
                    const float v = D[st][r];
                    float s2 = v * v;
                    if (diag) {
                        const int kr = st * 32 + (r & 3) + 8 * (r >> 2) + 4 * lh;
                        // q-row within the 64-row tile = qs*32 + lq  (r12 bug: dropped qs*32)
                        s2 = (kr <= qs * 32 + lq) ? s2 : 0.f;
                    }
                    zl += s2;
                    D[st][r] = s2;
                }
            // phase 2: O += P @ V; P A-frags assembled in-register (verified r11)
#pragma unroll
            for (int ks = 0; ks < 4; ++ks) {
                const int st = ks >> 1, b = 8 * (ks & 1);
                const bf16x8 vb0 = *(const bf16x8*)&vsl[cur][((2 * ks + lh) * 64 + 0 * 32 + lq) * 8];
                const bf16x8 vb1 = *(const bf16x8*)&vsl[cur][((2 * ks + lh) * 64 + 1 * 32 + lq) * 8];
                unsigned u0 = pk2(D[st][b + 0], D[st][b + 1]);
                unsigned u1 = pk2(D[st][b + 2], D[st][b + 3]);
                unsigned v0 = pk2(D[st][b + 4], D[st][b + 5]);
                unsigned v1 = pk2(D[st][b + 6], D[st][b + 7]);
                asm("v_permlane32_swap_b32 %0, %1" : "+v"(u0), "+v"(v0));
                asm("v_permlane32_swap_b32 %0, %1" : "+v"(u1), "+v"(v1));
                uint4v pw; pw[0] = u0; pw[1] = u1; pw[2] = v0; pw[3] = v1;
                const bf16x8 pa = __builtin_bit_cast(bf16x8, pw);
                oacc[0] = __builtin_amdgcn_mfma_f32_32x32x16_bf16(pa, vb0, oacc[0], 0, 0, 0);
                oacc[1] = __builtin_amdgcn_mfma_f32_32x32x16_bf16(pa, vb1, oacc[1], 0, 0, 0);
            }
        }

        if (pf) {
            if (wid < 4) asm volatile("s_waitcnt vmcnt(2)" ::: "memory");
            else         asm volatile("s_waitcnt vmcnt(1)" ::: "memory");
        } else {
            asm volatile("s_waitcnt vmcnt(0)" ::: "memory");
        }
        __builtin_amdgcn_s_barrier();
    }
#undef STAGE_KV

    // z finalize: halves lh=0/1 hold complementary k partial sums for q=lq
    {
        const float z = zl + __shfl_xor(zl, 32);
        if (lh == 0) zbuf[wid][lq] = 1.f / (z + 1e-5f);
    }
    // wave-local zbuf (written+read by same wave)
#pragma unroll
    for (int dt = 0; dt < 2; ++dt)
#pragma unroll
        for (int r = 0; r < 16; ++r) {
            const int qr = (r & 3) + 8 * (r >> 2) + 4 * lh;
            const float zi = zbuf[wid][qr];
            obh[(size_t)(qt * 64 + qs * 32 + qr) * 1024 + dt * 32 + lq] =
                f2b(oacc[dt][r] * zi);
        }
}

extern "C" void kernel_launch(void* const* d_in, const int* in_sizes, int n_in,
                              void* d_out, int out_size, void* d_ws, size_t ws_size,
                              hipStream_t stream) {
    const float* x     = (const float*)d_in[0];
    const float* Wq    = (const float*)d_in[1];
    const float* Wk    = (const float*)d_in[2];
    const float* Wv    = (const float*)d_in[3];
    const float* Wo    = (const float*)d_in[4];
    const float* gamma = (const float*)d_in[5];
    const float* beta  = (const float*)d_in[6];
    float* out = (float*)d_out;
    (void)in_sizes; (void)n_in; (void)out_size; (void)ws_size;

    char* w = (char*)d_ws;
    float*          qk_raw = (float*)w;                                   // 8 MB @ 0
    unsigned short* vTb    = (unsigned short*)(w + (8u  << 20));          // 8 MB [bh][64][2048]
    unsigned short* ob     = (unsigned short*)(w + (16u << 20));          // 8 MB
    unsigned short* xh     = (unsigned short*)(w + (24u << 20));          // 8 MB (dead after gemms)
    unsigned short* xl     = (unsigned short*)(w + (32u << 20));          // 8 MB (dead after gemm_split)
    unsigned short* qhl_g  = (unsigned short*)(w + (24u << 20));          // 4 MB (overlays dead xh)
    unsigned short* khl_g  = (unsigned short*)(w + (28u << 20));          // 4 MB (overlays dead xh)
    unsigned short* wqkh   = (unsigned short*)(w + (40u << 20));          // 1 MB
    unsigned short* wqkl   = (unsigned short*)(w + (41u << 20));          // 1 MB
    unsigned short* wvb    = (unsigned short*)(w + (42u << 20));          // 2 MB
    unsigned short* wob    = (unsigned short*)(w + (44u << 20));          // 2 MB

    cast_split<<<2048, 256, 0, stream>>>(x,  xh, xl, 4096 * 1024);
    cast_split<<<128,  256, 0, stream>>>(Wq, wqkh, wqkl, 256 * 1024);
    cast_split<<<128,  256, 0, stream>>>(Wk, wqkh + 256 * 1024, wqkl + 256 * 1024, 256 * 1024);
    cast_bf16 <<<512,  256, 0, stream>>>(Wv, wvb, 1024 * 1024);
    cast_bf16 <<<512,  256, 0, stream>>>(Wo, wob, 1024 * 1024);

    // qk projection (split-bf16, ~fp32): [4096][512] f32
    gemm_split<<<dim3(64, 8), 256, 0, stream>>>(xh, xl, wqkh, wqkl, qk_raw, 4096, 512, 1024);
    // v projection -> transposed bf16 vT[bh][d][l]
    gemm_mfma<64, 64, 2><<<dim3(64, 16), 256, 0, stream>>>(xh, wvb, vTb, 4096, 1024, 1024);
    // feature map -> q/k hi|lo bf16 [bh][l][32]
    ln_featuremap<<<512, 256, 0, stream>>>(qk_raw, gamma, beta, qhl_g, khl_g);
    // attention -> bf16 ob; 8-wave quad blocks (2 subtile-waves per tile)
    rebased_attn<<<dim3(32, 8), 512, 0, stream>>>(qhl_g, khl_g, vTb, ob);
    // output projection -> f32 out
    gemm_mfma<64, 64, 0><<<dim3(64, 16), 256, 0, stream>>>(ob, wob, out, 4096, 1024, 1024);
}

// Round 14
// 119.713 us; speedup vs baseline: 1.2536x; 1.0152x over previous
//
#include <hip/hip_runtime.h>
#include <cstddef>
#include <cstdint>

// ReBased linear attention, round 14.
// r13 post-mortem: no single kernel dominates (attn ~35us, GEMMs ~55-60us
// combined). Cheapest verified lever: v/o GEMMs 64x64 -> 128x64 tiles
// (MFMA/ds_read density 1.0 -> 1.33, 2 blocks/CU), template-args-only change.
// Attn: + s_setprio(1/0) around active compute (T5; role-split present).

typedef __attribute__((ext_vector_type(8)))  __bf16 bf16x8;
typedef __attribute__((ext_vector_type(2)))  __bf16 bf16x2;
typedef __attribute__((ext_vector_type(4)))  float  f32x4;
typedef __attribute__((ext_vector_type(16))) float  f32x16;
typedef __attribute__((ext_vector_type(8)))  unsigned short ushort8;
typedef __attribute__((ext_vector_type(4)))  unsigned short ushort4v;
typedef __attribute__((ext_vector_type(4)))  unsigned int   uint4v;

__device__ __forceinline__ unsigned short f2b(float f) {
    union { float f; unsigned u; } v; v.f = f;
    unsigned r = v.u + 0x7FFFu + ((v.u >> 16) & 1u);   // RNE
    return (unsigned short)(r >> 16);
}
__device__ __forceinline__ float b2f(unsigned short b) {
    union { unsigned u; float f; } v; v.u = ((unsigned)b) << 16;
    return v.f;
}
__device__ __forceinline__ unsigned pk2(float a, float b) {
    bf16x2 p; p[0] = (__bf16)a; p[1] = (__bf16)b;
    return __builtin_bit_cast(unsigned, p);
}

typedef const __attribute__((address_space(1))) void* gas_ptr;
typedef __attribute__((address_space(3))) void* las_ptr;

__device__ __forceinline__ void gload_lds16(const unsigned short* g, unsigned short* l) {
    // 16B/lane; LDS dest = wave-uniform base + lane*16
    __builtin_amdgcn_global_load_lds((gas_ptr)g, (las_ptr)l, 16, 0, 0);
}

// ---------------- bf16 MFMA GEMM, 2-phase dbuf: C = A @ W^T ----------------
// 256 threads = 4 waves (2x2). OUTMODE: 0=f32, 1=bf16, 2=bf16 vT scatter.
template <int BM, int BN, int OUTMODE>
__global__ __launch_bounds__(256) void gemm_mfma(const unsigned short* __restrict__ A,
                                                 const unsigned short* __restrict__ W,
                                                 void* __restrict__ Cout,
                                                 int M, int N, int K) {
    constexpr int BK = 64;
    constexpr int MF = BM / 32;
    constexpr int NF = BN / 32;
    __shared__ __align__(16) unsigned short As[2][BM * BK];
    __shared__ __align__(16) unsigned short Bs[2][BN * BK];

    const int t = threadIdx.x;
    const int wid = t >> 6, lane = t & 63;
    const int m0 = blockIdx.x * BM, n0 = blockIdx.y * BN;
    const int wrow = (wid >> 1) * (BM / 2);
    const int wcol = (wid & 1) * (BN / 2);
    const int lr = lane & 15, lk = (lane >> 4) * 8;

    f32x4 acc[MF][NF];
#pragma unroll
    for (int m = 0; m < MF; ++m)
#pragma unroll
        for (int n = 0; n < NF; ++n) acc[m][n] = (f32x4){0.f, 0.f, 0.f, 0.f};

    const unsigned short* Ag = A + (size_t)m0 * K;
    const unsigned short* Wg = W + (size_t)n0 * K;

#define G_STAGE(k0_, buf_)                                                        \
    do {                                                                          \
        _Pragma("unroll")                                                         \
        for (int i = 0; i < BM / 32; ++i) {                                       \
            const int e = (i * 256 + wid * 64 + lane) * 8;                        \
            gload_lds16(Ag + (size_t)(e >> 6) * K + (k0_) + (e & 63),             \
                        &As[buf_][(size_t)(i * 256 + wid * 64) * 8]);             \
        }                                                                         \
        _Pragma("unroll")                                                         \
        for (int i = 0; i < BN / 32; ++i) {                                       \
            const int e = (i * 256 + wid * 64 + lane) * 8;                        \
            gload_lds16(Wg + (size_t)(e >> 6) * K + (k0_) + (e & 63),             \
                        &Bs[buf_][(size_t)(i * 256 + wid * 64) * 8]);             \
        }                                                                         \
    } while (0)

    const int nk = K / BK;
    G_STAGE(0, 0);
    __syncthreads();

    for (int ki = 0; ki < nk; ++ki) {
        const int cur = ki & 1;
        if (ki + 1 < nk) G_STAGE((ki + 1) * BK, cur ^ 1);   // overlaps compute

#pragma unroll
        for (int kk = 0; kk < BK; kk += 32) {
            bf16x8 af[MF], bf[NF];
#pragma unroll
            for (int m = 0; m < MF; ++m)
                af[m] = *(const bf16x8*)&As[cur][(wrow + m * 16 + lr) * BK + kk + lk];
#pragma unroll
            for (int n = 0; n < NF; ++n)
                bf[n] = *(const bf16x8*)&Bs[cur][(wcol + n * 16 + lr) * BK + kk + lk];
#pragma unroll
            for (int m = 0; m < MF; ++m)
#pragma unroll
                for (int n = 0; n < NF; ++n)
                    acc[m][n] = __builtin_amdgcn_mfma_f32_16x16x32_bf16(af[m], bf[n], acc[m][n], 0, 0, 0);
        }
        __syncthreads();
    }
#undef G_STAGE

    const int orow0 = m0 + wrow + (lane >> 4) * 4;
    const int ocol0 = n0 + wcol + lr;
#pragma unroll
    for (int m = 0; m < MF; ++m)
#pragma unroll
        for (int n = 0; n < NF; ++n) {
            if (OUTMODE == 2) {
                const int nc = ocol0 + n * 16;
                const int mrow = orow0 + m * 16;
                unsigned short* dst = (unsigned short*)Cout
                    + (size_t)((mrow >> 11) * 16 + (nc >> 6)) * (64 * 2048)
                    + (size_t)(nc & 63) * 2048 + (mrow & 2047);
                ushort4v pv;
#pragma unroll
                for (int i = 0; i < 4; ++i) pv[i] = f2b(acc[m][n][i]);
                *(ushort4v*)dst = pv;
            } else {
#pragma unroll
                for (int i = 0; i < 4; ++i) {
                    const size_t idx = (size_t)(orow0 + m * 16 + i) * N + ocol0 + n * 16;
                    if (OUTMODE == 1) ((unsigned short*)Cout)[idx] = f2b(acc[m][n][i]);
                    else              ((float*)Cout)[idx] = acc[m][n][i];
                }
            }
        }
}

// ------- split-bf16 GEMM (qk projection), 2-phase dbuf, BM=BN=64 -------
__global__ __launch_bounds__(256) void gemm_split(const unsigned short* __restrict__ Ah,
                                                  const unsigned short* __restrict__ Al,
                                                  const unsigned short* __restrict__ Wh,
                                                  const unsigned short* __restrict__ Wl,
                                                  float* __restrict__ C,
                                                  int M, int N, int K) {
    constexpr int BM = 64, BN = 64, BK = 64;
    constexpr int MF = 2, NF = 2;
    __shared__ __align__(16) unsigned short Ahs[2][BM * BK];
    __shared__ __align__(16) unsigned short Als[2][BM * BK];
    __shared__ __align__(16) unsigned short Bhs[2][BN * BK];
    __shared__ __align__(16) unsigned short Bls[2][BN * BK];

    const int t = threadIdx.x;
    const int wid = t >> 6, lane = t & 63;
    const int m0 = blockIdx.x * BM, n0 = blockIdx.y * BN;
    const int wrow = (wid >> 1) * 32;
    const int wcol = (wid & 1) * 32;
    const int lr = lane & 15, lk = (lane >> 4) * 8;

    f32x4 acc[MF][NF];
#pragma unroll
    for (int m = 0; m < MF; ++m)
#pragma unroll
        for (int n = 0; n < NF; ++n) acc[m][n] = (f32x4){0.f, 0.f, 0.f, 0.f};

    const unsigned short* Ahg = Ah + (size_t)m0 * K;
    const unsigned short* Alg = Al + (size_t)m0 * K;
    const unsigned short* Whg = Wh + (size_t)n0 * K;
    const unsigned short* Wlg = Wl + (size_t)n0 * K;

#define S_STAGE(k0_, buf_)                                                        \
    do {                                                                          \
        _Pragma("unroll")                                                         \
        for (int i = 0; i < 2; ++i) {                                             \
            const int e = (i * 256 + wid * 64 + lane) * 8;                        \
            const size_t go = (size_t)(e >> 6) * K + (k0_) + (e & 63);            \
            const size_t lo = (size_t)(i * 256 + wid * 64) * 8;                   \
            gload_lds16(Ahg + go, &Ahs[buf_][lo]);                                \
            gload_lds16(Alg + go, &Als[buf_][lo]);                                \
            gload_lds16(Whg + go, &Bhs[buf_][lo]);                                \
            gload_lds16(Wlg + go, &Bls[buf_][lo]);                                \
        }                                                                         \
    } while (0)

    const int nk = K / BK;
    S_STAGE(0, 0);
    __syncthreads();

    for (int ki = 0; ki < nk; ++ki) {
        const int cur = ki & 1;
        if (ki + 1 < nk) S_STAGE((ki + 1) * BK, cur ^ 1);

#pragma unroll
        for (int kk = 0; kk < BK; kk += 32) {
            bf16x8 afh[MF], afl[MF], bfh[NF], bfl[NF];
#pragma unroll
            for (int m = 0; m < MF; ++m) {
                afh[m] = *(const bf16x8*)&Ahs[cur][(wrow + m * 16 + lr) * BK + kk + lk];
                afl[m] = *(const bf16x8*)&Als[cur][(wrow + m * 16 + lr) * BK + kk + lk];
            }
#pragma unroll
            for (int n = 0; n < NF; ++n) {
                bfh[n] = *(const bf16x8*)&Bhs[cur][(wcol + n * 16 + lr) * BK + kk + lk];
                bfl[n] = *(const bf16x8*)&Bls[cur][(wcol + n * 16 + lr) * BK + kk + lk];
            }
#pragma unroll
            for (int m = 0; m < MF; ++m)
#pragma unroll
                for (int n = 0; n < NF; ++n) {
                    acc[m][n] = __builtin_amdgcn_mfma_f32_16x16x32_bf16(afh[m], bfh[n], acc[m][n], 0, 0, 0);
                    acc[m][n] = __builtin_amdgcn_mfma_f32_16x16x32_bf16(afh[m], bfl[n], acc[m][n], 0, 0, 0);
                    acc[m][n] = __builtin_amdgcn_mfma_f32_16x16x32_bf16(afl[m], bfh[n], acc[m][n], 0, 0, 0);
                }
        }
        __syncthreads();
    }
#undef S_STAGE

    const int orow0 = m0 + wrow + (lane >> 4) * 4;
    const int ocol0 = n0 + wcol + lr;
#pragma unroll
    for (int m = 0; m < MF; ++m)
#pragma unroll
        for (int n = 0; n < NF; ++n)
#pragma unroll
            for (int i = 0; i < 4; ++i)
                C[(size_t)(orow0 + m * 16 + i) * N + ocol0 + n * 16] = acc[m][n][i];
}

// ---------------- f32 -> bf16 casts ----------------
__global__ __launch_bounds__(256) void cast_bf16(const float* __restrict__ in,
                                                 unsigned short* __restrict__ out, int n) {
    const int i = (blockIdx.x * 256 + threadIdx.x) * 8;
    if (i >= n) return;
    float4 a = *(const float4*)(in + i);
    float4 b = *(const float4*)(in + i + 4);
    ushort8 o;
    o[0] = f2b(a.x); o[1] = f2b(a.y); o[2] = f2b(a.z); o[3] = f2b(a.w);
    o[4] = f2b(b.x); o[5] = f2b(b.y); o[6] = f2b(b.z); o[7] = f2b(b.w);
    *(ushort8*)(out + i) = o;
}

__global__ __launch_bounds__(256) void cast_split(const float* __restrict__ in,
                                                  unsigned short* __restrict__ hi,
                                                  unsigned short* __restrict__ lo, int n) {
    const int i = (blockIdx.x * 256 + threadIdx.x) * 8;
    if (i >= n) return;
    float4 a = *(const float4*)(in + i);
    float4 b = *(const float4*)(in + i + 4);
    float xv[8] = {a.x, a.y, a.z, a.w, b.x, b.y, b.z, b.w};
    ushort8 oh, ol;
#pragma unroll
    for (int e = 0; e < 8; ++e) {
        const unsigned short h = f2b(xv[e]);
        oh[e] = h;
        ol[e] = f2b(xv[e] - b2f(h));
    }
    *(ushort8*)(hi + i) = oh;
    *(ushort8*)(lo + i) = ol;
}

// ------- feature map: qk_raw f32 -> q/k split hi|lo bf16 [bh][l][32] -------
__global__ __launch_bounds__(256) void ln_featuremap(const float* __restrict__ qk,
                                                     const float* __restrict__ gamma,
                                                     const float* __restrict__ beta,
                                                     unsigned short* __restrict__ qhl,
                                                     unsigned short* __restrict__ khl) {
    const int gid = blockIdx.x * 256 + threadIdx.x;
    const int idx = gid & 31;
    const int m = gid >> 5;
    const int b = m >> 11, l = m & 2047;
    const int h = idx & 15;
    const float scale = (idx < 16) ? 0.25f : 1.0f;
    const float* p = qk + (size_t)gid * 16;

    float xv[16];
    float4 v0 = *(const float4*)(p + 0);
    float4 v1 = *(const float4*)(p + 4);
    float4 v2 = *(const float4*)(p + 8);
    float4 v3 = *(const float4*)(p + 12);
    xv[0]=v0.x; xv[1]=v0.y; xv[2]=v0.z; xv[3]=v0.w;
    xv[4]=v1.x; xv[5]=v1.y; xv[6]=v1.z; xv[7]=v1.w;
    xv[8]=v2.x; xv[9]=v2.y; xv[10]=v2.z; xv[11]=v2.w;
    xv[12]=v3.x; xv[13]=v3.y; xv[14]=v3.z; xv[15]=v3.w;

    float mu = 0.f;
#pragma unroll
    for (int f = 0; f < 16; ++f) mu += xv[f];
    mu *= 0.0625f;
    float var = 0.f;
#pragma unroll
    for (int f = 0; f < 16; ++f) { float d = xv[f] - mu; var = fmaf(d, d, var); }
    var *= 0.0625f;
    const float rs = rsqrtf(var + 1e-5f);

    ushort8 hi0, hi1, lo0, lo1;
#pragma unroll
    for (int f = 0; f < 16; ++f) {
        const float v = ((xv[f] - mu) * rs * gamma[f] + beta[f]) * scale;
        const unsigned short hb = f2b(v);
        const unsigned short lb = f2b(v - b2f(hb));
        if (f < 8) { hi0[f] = hb; lo0[f] = lb; }
        else       { hi1[f - 8] = hb; lo1[f - 8] = lb; }
    }
    unsigned short* dst = ((idx < 16) ? qhl : khl)
        + ((size_t)(b * 16 + h) * 2048 + l) * 32;
    *(ushort8*)(dst + 0)  = hi0;
    *(ushort8*)(dst + 8)  = hi1;
    *(ushort8*)(dst + 16) = lo0;
    *(ushort8*)(dst + 24) = lo1;
}

// ------- causal (q.k)^2 attention: 32x32 MFMA, P-in-register, 8-wave blocks -------
// grid (32 bh, 8 x). 512 thr = 8 waves; wave w: q-tile quad[w>>1], subtile w&1
// (32 q-rows). qhl/khl: [bh][l][32]=[hi16|lo16]; vT: [bh][64][2048].
__global__ __launch_bounds__(512) void rebased_attn(const unsigned short* __restrict__ qhl_g,
                                                    const unsigned short* __restrict__ khl_g,
                                                    const unsigned short* __restrict__ vT,
                                                    unsigned short* __restrict__ o) {
    const int bh = blockIdx.x;
    const int x  = blockIdx.y;
    const int bb = bh >> 4;
    const int t = threadIdx.x;
    const int wid = t >> 6, lane = t & 63;
    const int lq = lane & 31, lh = lane >> 5;
    const int tq = wid >> 1, qs = wid & 1;
    const int qt = (tq == 0) ? x : (tq == 1) ? (15 - x) : (tq == 2) ? (16 + x) : (31 - x);
    const int qtmax = 31 - x;

    __shared__ __align__(16) unsigned short khl[3][4 * 64 * 8];   // [og][row][8] x3
    __shared__ __align__(16) unsigned short vsl[3][8 * 64 * 8];   // [og'][d][8] x3
    __shared__ float zbuf[8][32];

    const unsigned short* qg  = qhl_g + (size_t)bh * 2048 * 32;
    const unsigned short* kg  = khl_g + (size_t)bh * 2048 * 32;
    const unsigned short* vbh = vT + (size_t)bh * 64 * 2048;
    unsigned short*       obh = o  + (size_t)bb * 2048 * 1024 + (bh & 15) * 64;

    const f32x16 zc16 = (f32x16)(0.f);

    // Q B-frags in VGPRs: row = qt*64 + qs*32 + lq, octet lh (hi) / 2+lh (lo)
    const unsigned short* qr_ = qg + (size_t)(qt * 64 + qs * 32 + lq) * 32;
    const bf16x8 bqh = *(const bf16x8*)&qr_[lh * 8];
    const bf16x8 bql = *(const bf16x8*)&qr_[16 + lh * 8];

    // staging: K 4 chunks (waves 0-3), V 8 chunks (all waves)
#define STAGE_KV(kt_, buf_)                                                            \
    do {                                                                               \
        if (wid < 4)                                                                   \
            gload_lds16(kg + ((size_t)((kt_) << 6) + lane) * 32 + wid * 8,             \
                        &khl[buf_][wid * 512]);                                        \
        gload_lds16(vbh + (size_t)lane * 2048 + ((kt_) << 6) + wid * 8,                \
                    &vsl[buf_][wid * 512]);                                            \
    } while (0)

    STAGE_KV(0, 0);
    STAGE_KV(1, 1);
    if (wid < 4) asm volatile("s_waitcnt vmcnt(2)" ::: "memory");
    else         asm volatile("s_waitcnt vmcnt(1)" ::: "memory");
    __builtin_amdgcn_s_barrier();

    f32x16 oacc[2];
    oacc[0] = zc16; oacc[1] = zc16;
    float zl = 0.f;

    for (int kt = 0; kt <= qtmax; ++kt) {
        const int cur = kt % 3;
        const bool pf = (kt + 2 <= qtmax);
        if (pf) STAGE_KV(kt + 2, (kt + 2) % 3);

        if (kt <= qt) {   // wave-uniform: group still active
            __builtin_amdgcn_s_setprio(1);   // T5: favor compute waves
            // phase 1: S^T = K x Q via 3-term hi/lo 32x32x16 MFMAs
            f32x16 D[2];
#pragma unroll
            for (int st = 0; st < 2; ++st) {
                const bf16x8 kh = *(const bf16x8*)&khl[cur][((lh    ) * 64 + st * 32 + lq) * 8];
                const bf16x8 kl = *(const bf16x8*)&khl[cur][((2 + lh) * 64 + st * 32 + lq) * 8];
                f32x16 a = __builtin_amdgcn_mfma_f32_32x32x16_bf16(kh, bql, zc16, 0, 0, 0);
                a = __builtin_amdgcn_mfma_f32_32x32x16_bf16(kl, bqh, a, 0, 0, 0);
                a = __builtin_amdgcn_mfma_f32_32x32x16_bf16(kh, bqh, a, 0, 0, 0);
                D[st] = a;
            }
            // square + causal mask (diag only) + z accum
            const bool diag = (kt == qt);
#pragma unroll
            for (int st = 0; st < 2; ++st)
#pragma unroll
                for (int r = 0; r < 16; ++r) {
                    const float v = D[st][r];
                    float s2 = v * v;
                    if (diag) {
                        const int kr = st * 32 + (r & 3) + 8 * (r >> 2) + 4 * lh;
                        s2 = (kr <= qs * 32 + lq) ? s2 : 0.f;   // q-row = qs*32+lq
                    }
                    zl += s2;
                    D[st][r] = s2;
                }
            // phase 2: O += P @ V; P A-frags assembled in-register (verified r11)
#pragma unroll
            for (int ks = 0; ks < 4; ++ks) {
                const int st = ks >> 1, b = 8 * (ks & 1);
                const bf16x8 vb0 = *(const bf16x8*)&vsl[cur][((2 * ks + lh) * 64 + 0 * 32 + lq) * 8];
                const bf16x8 vb1 = *(const bf16x8*)&vsl[cur][((2 * ks + lh) * 64 + 1 * 32 + lq) * 8];
                unsigned u0 = pk2(D[st][b + 0], D[st][b + 1]);
                unsigned u1 = pk2(D[st][b + 2], D[st][b + 3]);
                unsigned v0 = pk2(D[st][b + 4], D[st][b + 5]);
                unsigned v1 = pk2(D[st][b + 6], D[st][b + 7]);
                asm("v_permlane32_swap_b32 %0, %1" : "+v"(u0), "+v"(v0));
                asm("v_permlane32_swap_b32 %0, %1" : "+v"(u1), "+v"(v1));
                uint4v pw; pw[0] = u0; pw[1] = u1; pw[2] = v0; pw[3] = v1;
                const bf16x8 pa = __builtin_bit_cast(bf16x8, pw);
                oacc[0] = __builtin_amdgcn_mfma_f32_32x32x16_bf16(pa, vb0, oacc[0], 0, 0, 0);
                oacc[1] = __builtin_amdgcn_mfma_f32_32x32x16_bf16(pa, vb1, oacc[1], 0, 0, 0);
            }
            __builtin_amdgcn_s_setprio(0);
        }

        if (pf) {
            if (wid < 4) asm volatile("s_waitcnt vmcnt(2)" ::: "memory");
            else         asm volatile("s_waitcnt vmcnt(1)" ::: "memory");
        } else {
            asm volatile("s_waitcnt vmcnt(0)" ::: "memory");
        }
        __builtin_amdgcn_s_barrier();
    }
#undef STAGE_KV

    // z finalize: halves lh=0/1 hold complementary k partial sums for q=lq
    {
        const float z = zl + __shfl_xor(zl, 32);
        if (lh == 0) zbuf[wid][lq] = 1.f / (z + 1e-5f);
    }
    // wave-local zbuf (written+read by same wave)
#pragma unroll
    for (int dt = 0; dt < 2; ++dt)
#pragma unroll
        for (int r = 0; r < 16; ++r) {
            const int qr = (r & 3) + 8 * (r >> 2) + 4 * lh;
            const float zi = zbuf[wid][qr];
            obh[(size_t)(qt * 64 + qs * 32 + qr) * 1024 + dt * 32 + lq] =
                f2b(oacc[dt][r] * zi);
        }
}

extern "C" void kernel_launch(void* const* d_in, const int* in_sizes, int n_in,
                              void* d_out, int out_size, void* d_ws, size_t ws_size,
                              hipStream_t stream) {
    const float* x     = (const float*)d_in[0];
    const float* Wq    = (const float*)d_in[1];
    const float* Wk    = (const float*)d_in[2];
    const float* Wv    = (const float*)d_in[3];
    const float* Wo    = (const float*)d_in[4];
    const float* gamma = (const float*)d_in[5];
    const float* beta  = (const float*)d_in[6];
    float* out = (float*)d_out;
    (void)in_sizes; (void)n_in; (void)out_size; (void)ws_size;

    char* w = (char*)d_ws;
    float*          qk_raw = (float*)w;                                   // 8 MB @ 0
    unsigned short* vTb    = (unsigned short*)(w + (8u  << 20));          // 8 MB [bh][64][2048]
    unsigned short* ob     = (unsigned short*)(w + (16u << 20));          // 8 MB
    unsigned short* xh     = (unsigned short*)(w + (24u << 20));          // 8 MB (dead after gemms)
    unsigned short* xl     = (unsigned short*)(w + (32u << 20));          // 8 MB (dead after gemm_split)
    unsigned short* qhl_g  = (unsigned short*)(w + (24u << 20));          // 4 MB (overlays dead xh)
    unsigned short* khl_g  = (unsigned short*)(w + (28u << 20));          // 4 MB (overlays dead xh)
    unsigned short* wqkh   = (unsigned short*)(w + (40u << 20));          // 1 MB
    unsigned short* wqkl   = (unsigned short*)(w + (41u << 20));          // 1 MB
    unsigned short* wvb    = (unsigned short*)(w + (42u << 20));          // 2 MB
    unsigned short* wob    = (unsigned short*)(w + (44u << 20));          // 2 MB

    cast_split<<<2048, 256, 0, stream>>>(x,  xh, xl, 4096 * 1024);
    cast_split<<<128,  256, 0, stream>>>(Wq, wqkh, wqkl, 256 * 1024);
    cast_split<<<128,  256, 0, stream>>>(Wk, wqkh + 256 * 1024, wqkl + 256 * 1024, 256 * 1024);
    cast_bf16 <<<512,  256, 0, stream>>>(Wv, wvb, 1024 * 1024);
    cast_bf16 <<<512,  256, 0, stream>>>(Wo, wob, 1024 * 1024);

    // qk projection (split-bf16, ~fp32): [4096][512] f32
    gemm_split<<<dim3(64, 8), 256, 0, stream>>>(xh, xl, wqkh, wqkl, qk_raw, 4096, 512, 1024);
    // v projection -> transposed bf16 vT[bh][d][l]; 128x64 tiles, grid 512
    gemm_mfma<128, 64, 2><<<dim3(32, 16), 256, 0, stream>>>(xh, wvb, vTb, 4096, 1024, 1024);
    // feature map -> q/k hi|lo bf16 [bh][l][32]
    ln_featuremap<<<512, 256, 0, stream>>>(qk_raw, gamma, beta, qhl_g, khl_g);
    // attention -> bf16 ob; 8-wave quad blocks (2 subtile-waves per tile)
    rebased_attn<<<dim3(32, 8), 512, 0, stream>>>(qhl_g, khl_g, vTb, ob);
    // output projection -> f32 out; 128x64 tiles, grid 512
    gemm_mfma<128, 64, 0><<<dim3(32, 16), 256, 0, stream>>>(ob, wob, out, 4096, 1024, 1024);
}

// Round 15
// 116.510 us; speedup vs baseline: 1.2881x; 1.0275x over previous
//
#include <hip/hip_runtime.h>
#include <cstddef>
#include <cstdint>

// ReBased linear attention, round 15.
// r14 post-mortem: no dominant kernel; remaining fat = plumbing (10 launches,
// LN pass re-reads 8MB qk_raw). Fuse LN feature-map INTO gemm_split epilogue:
// lanes lr=0..15 of a quarter-wave hold one full head (col%16==lr) -> LN
// reduction = 4 shfl_xor; write q/k hi|lo bf16 directly. Deletes ln kernel +
// 16MB traffic. Merge Wq+Wk and Wv+Wo casts (2 fewer launches).

typedef __attribute__((ext_vector_type(8)))  __bf16 bf16x8;
typedef __attribute__((ext_vector_type(2)))  __bf16 bf16x2;
typedef __attribute__((ext_vector_type(4)))  float  f32x4;
typedef __attribute__((ext_vector_type(16))) float  f32x16;
typedef __attribute__((ext_vector_type(8)))  unsigned short ushort8;
typedef __attribute__((ext_vector_type(4)))  unsigned short ushort4v;
typedef __attribute__((ext_vector_type(4)))  unsigned int   uint4v;

__device__ __forceinline__ unsigned short f2b(float f) {
    union { float f; unsigned u; } v; v.f = f;
    unsigned r = v.u + 0x7FFFu + ((v.u >> 16) & 1u);   // RNE
    return (unsigned short)(r >> 16);
}
__device__ __forceinline__ float b2f(unsigned short b) {
    union { unsigned u; float f; } v; v.u = ((unsigned)b) << 16;
    return v.f;
}
__device__ __forceinline__ unsigned pk2(float a, float b) {
    bf16x2 p; p[0] = (__bf16)a; p[1] = (__bf16)b;
    return __builtin_bit_cast(unsigned, p);
}

typedef const __attribute__((address_space(1))) void* gas_ptr;
typedef __attribute__((address_space(3))) void* las_ptr;

__device__ __forceinline__ void gload_lds16(const unsigned short* g, unsigned short* l) {
    // 16B/lane; LDS dest = wave-uniform base + lane*16
    __builtin_amdgcn_global_load_lds((gas_ptr)g, (las_ptr)l, 16, 0, 0);
}

// ---------------- bf16 MFMA GEMM, 2-phase dbuf: C = A @ W^T ----------------
// 256 threads = 4 waves (2x2). OUTMODE: 0=f32, 1=bf16, 2=bf16 vT scatter.
template <int BM, int BN, int OUTMODE>
__global__ __launch_bounds__(256) void gemm_mfma(const unsigned short* __restrict__ A,
                                                 const unsigned short* __restrict__ W,
                                                 void* __restrict__ Cout,
                                                 int M, int N, int K) {
    constexpr int BK = 64;
    constexpr int MF = BM / 32;
    constexpr int NF = BN / 32;
    __shared__ __align__(16) unsigned short As[2][BM * BK];
    __shared__ __align__(16) unsigned short Bs[2][BN * BK];

    const int t = threadIdx.x;
    const int wid = t >> 6, lane = t & 63;
    const int m0 = blockIdx.x * BM, n0 = blockIdx.y * BN;
    const int wrow = (wid >> 1) * (BM / 2);
    const int wcol = (wid & 1) * (BN / 2);
    const int lr = lane & 15, lk = (lane >> 4) * 8;

    f32x4 acc[MF][NF];
#pragma unroll
    for (int m = 0; m < MF; ++m)
#pragma unroll
        for (int n = 0; n < NF; ++n) acc[m][n] = (f32x4){0.f, 0.f, 0.f, 0.f};

    const unsigned short* Ag = A + (size_t)m0 * K;
    const unsigned short* Wg = W + (size_t)n0 * K;

#define G_STAGE(k0_, buf_)                                                        \
    do {                                                                          \
        _Pragma("unroll")                                                         \
        for (int i = 0; i < BM / 32; ++i) {                                       \
            const int e = (i * 256 + wid * 64 + lane) * 8;                        \
            gload_lds16(Ag + (size_t)(e >> 6) * K + (k0_) + (e & 63),             \
                        &As[buf_][(size_t)(i * 256 + wid * 64) * 8]);             \
        }                                                                         \
        _Pragma("unroll")                                                         \
        for (int i = 0; i < BN / 32; ++i) {                                       \
            const int e = (i * 256 + wid * 64 + lane) * 8;                        \
            gload_lds16(Wg + (size_t)(e >> 6) * K + (k0_) + (e & 63),             \
                        &Bs[buf_][(size_t)(i * 256 + wid * 64) * 8]);             \
        }                                                                         \
    } while (0)

    const int nk = K / BK;
    G_STAGE(0, 0);
    __syncthreads();

    for (int ki = 0; ki < nk; ++ki) {
        const int cur = ki & 1;
        if (ki + 1 < nk) G_STAGE((ki + 1) * BK, cur ^ 1);   // overlaps compute

#pragma unroll
        for (int kk = 0; kk < BK; kk += 32) {
            bf16x8 af[MF], bf[NF];
#pragma unroll
            for (int m = 0; m < MF; ++m)
                af[m] = *(const bf16x8*)&As[cur][(wrow + m * 16 + lr) * BK + kk + lk];
#pragma unroll
            for (int n = 0; n < NF; ++n)
                bf[n] = *(const bf16x8*)&Bs[cur][(wcol + n * 16 + lr) * BK + kk + lk];
#pragma unroll
            for (int m = 0; m < MF; ++m)
#pragma unroll
                for (int n = 0; n < NF; ++n)
                    acc[m][n] = __builtin_amdgcn_mfma_f32_16x16x32_bf16(af[m], bf[n], acc[m][n], 0, 0, 0);
        }
        __syncthreads();
    }
#undef G_STAGE

    const int orow0 = m0 + wrow + (lane >> 4) * 4;
    const int ocol0 = n0 + wcol + lr;
#pragma unroll
    for (int m = 0; m < MF; ++m)
#pragma unroll
        for (int n = 0; n < NF; ++n) {
            if (OUTMODE == 2) {
                const int nc = ocol0 + n * 16;
                const int mrow = orow0 + m * 16;
                unsigned short* dst = (unsigned short*)Cout
                    + (size_t)((mrow >> 11) * 16 + (nc >> 6)) * (64 * 2048)
                    + (size_t)(nc & 63) * 2048 + (mrow & 2047);
                ushort4v pv;
#pragma unroll
                for (int i = 0; i < 4; ++i) pv[i] = f2b(acc[m][n][i]);
                *(ushort4v*)dst = pv;
            } else {
#pragma unroll
                for (int i = 0; i < 4; ++i) {
                    const size_t idx = (size_t)(orow0 + m * 16 + i) * N + ocol0 + n * 16;
                    if (OUTMODE == 1) ((unsigned short*)Cout)[idx] = f2b(acc[m][n][i]);
                    else              ((float*)Cout)[idx] = acc[m][n][i];
                }
            }
        }
}

// ------- split-bf16 GEMM (qk projection) + FUSED LN feature-map epilogue -------
// BM=BN=64, 2-phase dbuf. Output: qhl/khl [bh][l][32]=[hi16|lo16] directly.
// Epilogue: lanes lr=0..15 of a quarter-wave hold cols head*16+lr of one row
// -> LN reduce via shfl_xor(1,2,4,8); q heads (col<256) scaled by 0.25.
__global__ __launch_bounds__(256) void gemm_split_ln(const unsigned short* __restrict__ Ah,
                                                     const unsigned short* __restrict__ Al,
                                                     const unsigned short* __restrict__ Wh,
                                                     const unsigned short* __restrict__ Wl,
                                                     const float* __restrict__ gamma,
                                                     const float* __restrict__ beta,
                                                     unsigned short* __restrict__ qhl,
                                                     unsigned short* __restrict__ khl,
                                                     int M, int N, int K) {
    constexpr int BM = 64, BN = 64, BK = 64;
    constexpr int MF = 2, NF = 2;
    __shared__ __align__(16) unsigned short Ahs[2][BM * BK];
    __shared__ __align__(16) unsigned short Als[2][BM * BK];
    __shared__ __align__(16) unsigned short Bhs[2][BN * BK];
    __shared__ __align__(16) unsigned short Bls[2][BN * BK];

    const int t = threadIdx.x;
    const int wid = t >> 6, lane = t & 63;
    const int m0 = blockIdx.x * BM, n0 = blockIdx.y * BN;
    const int wrow = (wid >> 1) * 32;
    const int wcol = (wid & 1) * 32;
    const int lr = lane & 15, lk = (lane >> 4) * 8;

    f32x4 acc[MF][NF];
#pragma unroll
    for (int m = 0; m < MF; ++m)
#pragma unroll
        for (int n = 0; n < NF; ++n) acc[m][n] = (f32x4){0.f, 0.f, 0.f, 0.f};

    const unsigned short* Ahg = Ah + (size_t)m0 * K;
    const unsigned short* Alg = Al + (size_t)m0 * K;
    const unsigned short* Whg = Wh + (size_t)n0 * K;
    const unsigned short* Wlg = Wl + (size_t)n0 * K;

#define S_STAGE(k0_, buf_)                                                        \
    do {                                                                          \
        _Pragma("unroll")                                                         \
        for (int i = 0; i < 2; ++i) {                                             \
            const int e = (i * 256 + wid * 64 + lane) * 8;                        \
            const size_t go = (size_t)(e >> 6) * K + (k0_) + (e & 63);            \
            const size_t lo = (size_t)(i * 256 + wid * 64) * 8;                   \
            gload_lds16(Ahg + go, &Ahs[buf_][lo]);                                \
            gload_lds16(Alg + go, &Als[buf_][lo]);                                \
            gload_lds16(Whg + go, &Bhs[buf_][lo]);                                \
            gload_lds16(Wlg + go, &Bls[buf_][lo]);                                \
        }                                                                         \
    } while (0)

    const int nk = K / BK;
    S_STAGE(0, 0);
    __syncthreads();

    for (int ki = 0; ki < nk; ++ki) {
        const int cur = ki & 1;
        if (ki + 1 < nk) S_STAGE((ki + 1) * BK, cur ^ 1);

#pragma unroll
        for (int kk = 0; kk < BK; kk += 32) {
            bf16x8 afh[MF], afl[MF], bfh[NF], bfl[NF];
#pragma unroll
            for (int m = 0; m < MF; ++m) {
                afh[m] = *(const bf16x8*)&Ahs[cur][(wrow + m * 16 + lr) * BK + kk + lk];
                afl[m] = *(const bf16x8*)&Als[cur][(wrow + m * 16 + lr) * BK + kk + lk];
            }
#pragma unroll
            for (int n = 0; n < NF; ++n) {
                bfh[n] = *(const bf16x8*)&Bhs[cur][(wcol + n * 16 + lr) * BK + kk + lk];
                bfl[n] = *(const bf16x8*)&Bls[cur][(wcol + n * 16 + lr) * BK + kk + lk];
            }
#pragma unroll
            for (int m = 0; m < MF; ++m)
#pragma unroll
                for (int n = 0; n < NF; ++n) {
                    acc[m][n] = __builtin_amdgcn_mfma_f32_16x16x32_bf16(afh[m], bfh[n], acc[m][n], 0, 0, 0);
                    acc[m][n] = __builtin_amdgcn_mfma_f32_16x16x32_bf16(afh[m], bfl[n], acc[m][n], 0, 0, 0);
                    acc[m][n] = __builtin_amdgcn_mfma_f32_16x16x32_bf16(afl[m], bfh[n], acc[m][n], 0, 0, 0);
                }
        }
        __syncthreads();
    }
#undef S_STAGE

    // fused LN + hi/lo split epilogue
    const int orow0 = m0 + wrow + (lane >> 4) * 4;
    const float gl = gamma[lr];
    const float bl = beta[lr];
#pragma unroll
    for (int n = 0; n < NF; ++n) {
        const int head_all = (n0 + wcol + n * 16) >> 4;     // 0..31
        const float scale = (head_all < 16) ? 0.25f : 1.0f;
        unsigned short* base = (head_all < 16) ? qhl : khl;
        const size_t hoff = (size_t)(head_all & 15) * (2048 * 32);  // + b*16*2048*32 later
#pragma unroll
        for (int m = 0; m < MF; ++m)
#pragma unroll
            for (int i = 0; i < 4; ++i) {
                const float v = acc[m][n][i];
                float s = v, sq = v * v;
#pragma unroll
                for (int msk = 1; msk < 16; msk <<= 1) {
                    s  += __shfl_xor(s,  msk);
                    sq += __shfl_xor(sq, msk);
                }
                const float mu  = s * 0.0625f;
                const float var = sq * 0.0625f - mu * mu;
                const float rs  = rsqrtf(var + 1e-5f);
                const float val = ((v - mu) * rs * gl + bl) * scale;
                const unsigned short hb = f2b(val);
                const unsigned short lb = f2b(val - b2f(hb));
                const int mrow = orow0 + m * 16 + i;         // 0..4095
                const int bb = mrow >> 11, l = mrow & 2047;
                unsigned short* dst = base + (size_t)bb * (16 * 2048 * 32) + hoff + (size_t)l * 32;
                dst[lr]      = hb;
                dst[16 + lr] = lb;
            }
    }
}

// ---------------- f32 -> bf16 casts (paired sources) ----------------
__global__ __launch_bounds__(256) void cast_bf16_2(const float* __restrict__ a,
                                                   const float* __restrict__ b,
                                                   unsigned short* __restrict__ oa,
                                                   unsigned short* __restrict__ ob_,
                                                   int na) {
    const int i = (blockIdx.x * 256 + threadIdx.x) * 8;
    const float* in = (i < na) ? a : b;
    unsigned short* out = (i < na) ? oa : ob_;
    const int j = (i < na) ? i : (i - na);
    float4 p = *(const float4*)(in + j);
    float4 q = *(const float4*)(in + j + 4);
    ushort8 o;
    o[0] = f2b(p.x); o[1] = f2b(p.y); o[2] = f2b(p.z); o[3] = f2b(p.w);
    o[4] = f2b(q.x); o[5] = f2b(q.y); o[6] = f2b(q.z); o[7] = f2b(q.w);
    *(ushort8*)(out + j) = o;
}

__global__ __launch_bounds__(256) void cast_split(const float* __restrict__ in,
                                                  unsigned short* __restrict__ hi,
                                                  unsigned short* __restrict__ lo, int n) {
    const int i = (blockIdx.x * 256 + threadIdx.x) * 8;
    if (i >= n) return;
    float4 a = *(const float4*)(in + i);
    float4 b = *(const float4*)(in + i + 4);
    float xv[8] = {a.x, a.y, a.z, a.w, b.x, b.y, b.z, b.w};
    ushort8 oh, ol;
#pragma unroll
    for (int e = 0; e < 8; ++e) {
        const unsigned short h = f2b(xv[e]);
        oh[e] = h;
        ol[e] = f2b(xv[e] - b2f(h));
    }
    *(ushort8*)(hi + i) = oh;
    *(ushort8*)(lo + i) = ol;
}

// Wq/Wk pair: hi/lo split, contiguous dest (Wk at +na)
__global__ __launch_bounds__(256) void cast_split2(const float* __restrict__ a,
                                                   const float* __restrict__ b,
                                                   unsigned short* __restrict__ hi,
                                                   unsigned short* __restrict__ lo,
                                                   int na) {
    const int i = (blockIdx.x * 256 + threadIdx.x) * 8;
    const float* in = (i < na) ? a : b;
    const int j = (i < na) ? i : (i - na);
    float4 p = *(const float4*)(in + j);
    float4 q = *(const float4*)(in + j + 4);
    float xv[8] = {p.x, p.y, p.z, p.w, q.x, q.y, q.z, q.w};
    ushort8 oh, ol;
#pragma unroll
    for (int e = 0; e < 8; ++e) {
        const unsigned short h = f2b(xv[e]);
        oh[e] = h;
        ol[e] = f2b(xv[e] - b2f(h));
    }
    *(ushort8*)(hi + i) = oh;
    *(ushort8*)(lo + i) = ol;
}

// ------- causal (q.k)^2 attention: 32x32 MFMA, P-in-register, 8-wave blocks -------
// grid (32 bh, 8 x). 512 thr = 8 waves; wave w: q-tile quad[w>>1], subtile w&1
// (32 q-rows). qhl/khl: [bh][l][32]=[hi16|lo16]; vT: [bh][64][2048].
__global__ __launch_bounds__(512) void rebased_attn(const unsigned short* __restrict__ qhl_g,
                                                    const unsigned short* __restrict__ khl_g,
                                                    const unsigned short* __restrict__ vT,
                                                    unsigned short* __restrict__ o) {
    const int bh = blockIdx.x;
    const int x  = blockIdx.y;
    const int bb = bh >> 4;
    const int t = threadIdx.x;
    const int wid = t >> 6, lane = t & 63;
    const int lq = lane & 31, lh = lane >> 5;
    const int tq = wid >> 1, qs = wid & 1;
    const int qt = (tq == 0) ? x : (tq == 1) ? (15 - x) : (tq == 2) ? (16 + x) : (31 - x);
    const int qtmax = 31 - x;

    __shared__ __align__(16) unsigned short khl[3][4 * 64 * 8];   // [og][row][8] x3
    __shared__ __align__(16) unsigned short vsl[3][8 * 64 * 8];   // [og'][d][8] x3
    __shared__ float zbuf[8][32];

    const unsigned short* qg  = qhl_g + (size_t)bh * 2048 * 32;
    const unsigned short* kg  = khl_g + (size_t)bh * 2048 * 32;
    const unsigned short* vbh = vT + (size_t)bh * 64 * 2048;
    unsigned short*       obh = o  + (size_t)bb * 2048 * 1024 + (bh & 15) * 64;

    const f32x16 zc16 = (f32x16)(0.f);

    // Q B-frags in VGPRs: row = qt*64 + qs*32 + lq, octet lh (hi) / 2+lh (lo)
    const unsigned short* qr_ = qg + (size_t)(qt * 64 + qs * 32 + lq) * 32;
    const bf16x8 bqh = *(const bf16x8*)&qr_[lh * 8];
    const bf16x8 bql = *(const bf16x8*)&qr_[16 + lh * 8];

    // staging: K 4 chunks (waves 0-3), V 8 chunks (all waves)
#define STAGE_KV(kt_, buf_)                                                            \
    do {                                                                               \
        if (wid < 4)                                                                   \
            gload_lds16(kg + ((size_t)((kt_) << 6) + lane) * 32 + wid * 8,             \
                        &khl[buf_][wid * 512]);                                        \
        gload_lds16(vbh + (size_t)lane * 2048 + ((kt_) << 6) + wid * 8,                \
                    &vsl[buf_][wid * 512]);                                            \
    } while (0)

    STAGE_KV(0, 0);
    STAGE_KV(1, 1);
    if (wid < 4) asm volatile("s_waitcnt vmcnt(2)" ::: "memory");
    else         asm volatile("s_waitcnt vmcnt(1)" ::: "memory");
    __builtin_amdgcn_s_barrier();

    f32x16 oacc[2];
    oacc[0] = zc16; oacc[1] = zc16;
    float zl = 0.f;

    for (int kt = 0; kt <= qtmax; ++kt) {
        const int cur = kt % 3;
        const bool pf = (kt + 2 <= qtmax);
        if (pf) STAGE_KV(kt + 2, (kt + 2) % 3);

        if (kt <= qt) {   // wave-uniform: group still active
            __builtin_amdgcn_s_setprio(1);
            // phase 1: S^T = K x Q via 3-term hi/lo 32x32x16 MFMAs
            f32x16 D[2];
#pragma unroll
            for (int st = 0; st < 2; ++st) {
                const bf16x8 kh = *(const bf16x8*)&khl[cur][((lh    ) * 64 + st * 32 + lq) * 8];
                const bf16x8 kl = *(const bf16x8*)&khl[cur][((2 + lh) * 64 + st * 32 + lq) * 8];
                f32x16 a = __builtin_amdgcn_mfma_f32_32x32x16_bf16(kh, bql, zc16, 0, 0, 0);
                a = __builtin_amdgcn_mfma_f32_32x32x16_bf16(kl, bqh, a, 0, 0, 0);
                a = __builtin_amdgcn_mfma_f32_32x32x16_bf16(kh, bqh, a, 0, 0, 0);
                D[st] = a;
            }
            // square + causal mask (diag only) + z accum
            const bool diag = (kt == qt);
#pragma unroll
            for (int st = 0; st < 2; ++st)
#pragma unroll
                for (int r = 0; r < 16; ++r) {
                    const float v = D[st][r];
                    float s2 = v * v;
                    if (diag) {
                        const int kr = st * 32 + (r & 3) + 8 * (r >> 2) + 4 * lh;
                        s2 = (kr <= qs * 32 + lq) ? s2 : 0.f;   // q-row = qs*32+lq
                    }
                    zl += s2;
                    D[st][r] = s2;
                }
            // phase 2: O += P @ V; P A-frags assembled in-register (verified r11)
#pragma unroll
            for (int ks = 0; ks < 4; ++ks) {
                const int st = ks >> 1, b = 8 * (ks & 1);
                const bf16x8 vb0 = *(const bf16x8*)&vsl[cur][((2 * ks + lh) * 64 + 0 * 32 + lq) * 8];
                const bf16x8 vb1 = *(const bf16x8*)&vsl[cur][((2 * ks + lh) * 64 + 1 * 32 + lq) * 8];
                unsigned u0 = pk2(D[st][b + 0], D[st][b + 1]);
                unsigned u1 = pk2(D[st][b + 2], D[st][b + 3]);
                unsigned v0 = pk2(D[st][b + 4], D[st][b + 5]);
                unsigned v1 = pk2(D[st][b + 6], D[st][b + 7]);
                asm("v_permlane32_swap_b32 %0, %1" : "+v"(u0), "+v"(v0));
                asm("v_permlane32_swap_b32 %0, %1" : "+v"(u1), "+v"(v1));
                uint4v pw; pw[0] = u0; pw[1] = u1; pw[2] = v0; pw[3] = v1;
                const bf16x8 pa = __builtin_bit_cast(bf16x8, pw);
                oacc[0] = __builtin_amdgcn_mfma_f32_32x32x16_bf16(pa, vb0, oacc[0], 0, 0, 0);
                oacc[1] = __builtin_amdgcn_mfma_f32_32x32x16_bf16(pa, vb1, oacc[1], 0, 0, 0);
            }
            __builtin_amdgcn_s_setprio(0);
        }

        if (pf) {
            if (wid < 4) asm volatile("s_waitcnt vmcnt(2)" ::: "memory");
            else         asm volatile("s_waitcnt vmcnt(1)" ::: "memory");
        } else {
            asm volatile("s_waitcnt vmcnt(0)" ::: "memory");
        }
        __builtin_amdgcn_s_barrier();
    }
#undef STAGE_KV

    // z finalize: halves lh=0/1 hold complementary k partial sums for q=lq
    {
        const float z = zl + __shfl_xor(zl, 32);
        if (lh == 0) zbuf[wid][lq] = 1.f / (z + 1e-5f);
    }
    // wave-local zbuf (written+read by same wave)
#pragma unroll
    for (int dt = 0; dt < 2; ++dt)
#pragma unroll
        for (int r = 0; r < 16; ++r) {
            const int qr = (r & 3) + 8 * (r >> 2) + 4 * lh;
            const float zi = zbuf[wid][qr];
            obh[(size_t)(qt * 64 + qs * 32 + qr) * 1024 + dt * 32 + lq] =
                f2b(oacc[dt][r] * zi);
        }
}

extern "C" void kernel_launch(void* const* d_in, const int* in_sizes, int n_in,
                              void* d_out, int out_size, void* d_ws, size_t ws_size,
                              hipStream_t stream) {
    const float* x     = (const float*)d_in[0];
    const float* Wq    = (const float*)d_in[1];
    const float* Wk    = (const float*)d_in[2];
    const float* Wv    = (const float*)d_in[3];
    const float* Wo    = (const float*)d_in[4];
    const float* gamma = (const float*)d_in[5];
    const float* beta  = (const float*)d_in[6];
    float* out = (float*)d_out;
    (void)in_sizes; (void)n_in; (void)out_size; (void)ws_size;

    char* w = (char*)d_ws;
    unsigned short* vTb    = (unsigned short*)(w + (8u  << 20));          // 8 MB [bh][64][2048]
    unsigned short* ob     = (unsigned short*)(w + (16u << 20));          // 8 MB
    unsigned short* xh     = (unsigned short*)(w + (24u << 20));          // 8 MB
    unsigned short* xl     = (unsigned short*)(w + (32u << 20));          // 8 MB
    unsigned short* qhl_g  = (unsigned short*)(w + (0u  << 20));          // 4 MB (old qk_raw slot)
    unsigned short* khl_g  = (unsigned short*)(w + (4u  << 20));          // 4 MB
    unsigned short* wqkh   = (unsigned short*)(w + (40u << 20));          // 1 MB
    unsigned short* wqkl   = (unsigned short*)(w + (41u << 20));          // 1 MB
    unsigned short* wvb    = (unsigned short*)(w + (42u << 20));          // 2 MB
    unsigned short* wob    = (unsigned short*)(w + (44u << 20));          // 2 MB

    // casts: x hi/lo; Wq+Wk hi/lo (one launch); Wv+Wo bf16 (one launch)
    cast_split<<<2048, 256, 0, stream>>>(x, xh, xl, 4096 * 1024);
    cast_split2<<<256, 256, 0, stream>>>(Wq, Wk, wqkh, wqkl, 256 * 1024);
    cast_bf16_2<<<1024, 256, 0, stream>>>(Wv, Wo, wvb, wob, 1024 * 1024);

    // qk projection + fused LN feature-map -> qhl/khl directly
    gemm_split_ln<<<dim3(64, 8), 256, 0, stream>>>(xh, xl, wqkh, wqkl,
                                                   gamma, beta, qhl_g, khl_g,
                                                   4096, 512, 1024);
    // v projection -> transposed bf16 vT[bh][d][l]; 128x64 tiles
    gemm_mfma<128, 64, 2><<<dim3(32, 16), 256, 0, stream>>>(xh, wvb, vTb, 4096, 1024, 1024);
    // attention -> bf16 ob; 8-wave quad blocks
    rebased_attn<<<dim3(32, 8), 512, 0, stream>>>(qhl_g, khl_g, vTb, ob);
    // output projection -> f32 out; 128x64 tiles
    gemm_mfma<128, 64, 0><<<dim3(32, 16), 256, 0, stream>>>(ob, wob, out, 4096, 1024, 1024);
}